// Round 3
// baseline (553.802 us; speedup 1.0000x reference)
//
#include <hip/hip_runtime.h>
#include <hip/hip_bf16.h>

typedef __hip_bfloat16 bf16;

__device__ __forceinline__ float bf2f(bf16 x){ return __bfloat162float(x); }
__device__ __forceinline__ bf16 f2bf(float x){ return __float2bfloat16(x); }
struct __align__(8) bf4v { bf16 x,y,z,w; };
__device__ __forceinline__ float4 ldb4(const bf16* p){
  ushort4 u = *(const ushort4*)p;
  float4 r;
  r.x = __uint_as_float(((unsigned)u.x)<<16);
  r.y = __uint_as_float(((unsigned)u.y)<<16);
  r.z = __uint_as_float(((unsigned)u.z)<<16);
  r.w = __uint_as_float(((unsigned)u.w)<<16);
  return r;
}
__device__ __forceinline__ void stb4(bf16* p, float4 v){
  bf4v t; t.x=f2bf(v.x); t.y=f2bf(v.y); t.z=f2bf(v.z); t.w=f2bf(v.w);
  *(bf4v*)p = t;
}

#define L_SEQ 2048
#define DPROJ 2568
#define NCHUNK 16
#define TCH 128

// ---------------- GEMM1: proj = u @ W_in + b_in (fp32 in, bf16 out, fp32 side-channel) ----------
__global__ void __launch_bounds__(256) gemm1(const float* __restrict__ A, const float* __restrict__ B,
                                             const float* __restrict__ bias, bf16* __restrict__ C,
                                             float* __restrict__ side, int M, int N, int K)
{
  const int BM=64, BN=64, BK=16;
  __shared__ __align__(16) float As[BK*68];
  __shared__ __align__(16) float Bs[BK*68];
  int col0 = blockIdx.x*BN, row0 = blockIdx.y*BM;
  int tid = threadIdx.x;
  int tr = tid >> 4, tc = tid & 15;
  float acc[4][4] = {};
  for (int k0 = 0; k0 < K; k0 += BK) {
    for (int e = tid; e < BM*BK; e += 256) {
      int r = e >> 4, kk = e & 15;
      As[kk*68 + r] = A[(size_t)(row0+r)*K + k0 + kk];
    }
    for (int e = tid; e < BK*BN; e += 256) {
      int kk = e >> 6, cc = e & 63;
      int gc = col0 + cc;
      Bs[kk*68 + cc] = (gc < N) ? B[(size_t)(k0+kk)*N + gc] : 0.f;
    }
    __syncthreads();
    #pragma unroll
    for (int kk = 0; kk < BK; kk++) {
      float4 a4 = *(const float4*)&As[kk*68 + tr*4];
      float4 b4 = *(const float4*)&Bs[kk*68 + tc*4];
      float av[4] = {a4.x,a4.y,a4.z,a4.w};
      float bv[4] = {b4.x,b4.y,b4.z,b4.w};
      #pragma unroll
      for (int m=0;m<4;m++)
        #pragma unroll
        for (int n=0;n<4;n++) acc[m][n] += av[m]*bv[n];
    }
    __syncthreads();
  }
  #pragma unroll
  for (int m=0;m<4;m++){
    int gr = row0 + tr*4 + m;
    #pragma unroll
    for (int n=0;n<4;n++){
      int gc = col0 + tc*4 + n;
      if (gc < N) {
        float v = acc[m][n] + bias[gc];
        if (gc >= 2560) side[gr*8 + (gc-2560)] = v;
        C[(size_t)gr*N + gc] = f2bf(v);
      }
    }
  }
}

// ---------------- K23: dt = softplus, lam = sigmoid, csdt = cumsum_l(dt) (single block) ---------
__global__ void k23(const float* __restrict__ dlraw, float* __restrict__ dtb,
                    float* __restrict__ lamb, float* __restrict__ csdt)
{
  __shared__ float dts[L_SEQ*4];
  __shared__ float segs[4][64];
  int tid = threadIdx.x;
  int g = tid & 3, seg = tid >> 2;
  for (int i = 0; i < 32; i++){
    int l = seg*32 + i;
    float dr = dlraw[l*8 + g];
    float lr = dlraw[l*8 + 4 + g];
    float dt = (dr > 15.f) ? dr : log1pf(__expf(dr));
    dts[l*4+g] = dt;
    dtb[l*4+g] = dt;
    lamb[l*4+g] = 1.f/(1.f+__expf(-lr));
  }
  __syncthreads();
  float s = 0.f;
  for (int i=0;i<32;i++) s += dts[(seg*32+i)*4 + g];
  segs[g][seg] = s;
  __syncthreads();
  if (tid < 4) { float run = 0.f; for (int q=0;q<64;q++){ float t = segs[tid][q]; segs[tid][q] = run; run += t; } }
  __syncthreads();
  float run = segs[g][seg];
  for (int i=0;i<32;i++){ int l = seg*32+i; run += dts[l*4+g]; csdt[l*4+g] = run; }
}

// ---------------- K4: rmsnorm + bias + RoPE -> Br, Cr (bf16, layout [l][g][n*2+r]) --------------
__global__ void k4_rmsrope(const bf16* __restrict__ proj, const float* __restrict__ wB, const float* __restrict__ wC,
                           const float* __restrict__ biasB, const float* __restrict__ biasC,
                           const float* __restrict__ theta_log, const float* __restrict__ csdt,
                           bf16* __restrict__ Br, bf16* __restrict__ Cr)
{
  int l = blockIdx.x;
  int tid = threadIdx.x;
  int g = tid >> 6, idx = tid & 63;   // one wave per group
  const bf16* pr = proj + (size_t)l*DPROJ;
  float bv = bf2f(pr[2048 + g*64 + idx]);
  float cv = bf2f(pr[2304 + g*64 + idx]);
  float sb = bv*bv, sc = cv*cv;
  #pragma unroll
  for (int off=32; off; off>>=1){ sb += __shfl_xor(sb, off); sc += __shfl_xor(sc, off); }
  float rb = rsqrtf(sb*(1.f/64.f) + 1e-5f);
  float rc = rsqrtf(sc*(1.f/64.f) + 1e-5f);
  float bm = bv*rb*wB[idx] + biasB[g*64+idx];
  float cm = cv*rc*wC[idx] + biasC[g*64+idx];
  int k = idx >> 2;
  float ang = csdt[l*4+g] * __expf(theta_log[g*16+k]);
  float ca = cosf(ang), sa = sinf(ang);
  float bp = __shfl_xor(bm, 2);
  float cp = __shfl_xor(cm, 2);
  bool is_im = (idx >> 1) & 1;
  float bo = is_im ? (bp*sa + bm*ca) : (bm*ca - bp*sa);
  float co = is_im ? (cp*sa + cm*ca) : (cm*ca - cp*sa);
  Br[((size_t)l*4+g)*64 + idx] = f2bf(bo);
  Cr[((size_t)l*4+g)*64 + idx] = f2bf(co);
}

// ---------------- K5: x_up[l][h][p*2+r] = silu(x) @ W_xup ----------------
__global__ void k5_xup(const bf16* __restrict__ proj, const float* __restrict__ Wx, bf16* __restrict__ xup)
{
  __shared__ __align__(16) float wsm[64*128];
  __shared__ float xs[1024];
  int l = blockIdx.x, tid = threadIdx.x;
  for (int e=tid;e<8192;e+=256) wsm[e] = Wx[e];
  for (int e=tid;e<1024;e+=256){ float v = bf2f(proj[(size_t)l*DPROJ+1024+e]); xs[e] = v/(1.f+__expf(-v)); }
  __syncthreads();
  int h = tid>>4, prb = (tid&15)*8;
  float acc[8] = {};
  for (int k=0;k<64;k++){
    float xv = xs[h*64+k];
    const float4* w4 = (const float4*)&wsm[k*128 + prb];
    float4 a = w4[0], b = w4[1];
    acc[0]+=xv*a.x; acc[1]+=xv*a.y; acc[2]+=xv*a.z; acc[3]+=xv*a.w;
    acc[4]+=xv*b.x; acc[5]+=xv*b.y; acc[6]+=xv*b.z; acc[7]+=xv*b.w;
  }
  bf16* o = xup + ((size_t)l*16+h)*128 + prb;
  stb4(o,   make_float4(acc[0],acc[1],acc[2],acc[3]));
  stb4(o+4, make_float4(acc[4],acc[5],acc[6],acc[7]));
}

// ---------------- K6: per (chunk,head): y_diag (regrouped trapezoid) + h_final ----------------
__global__ void __launch_bounds__(256) k6_scan(
  const bf16* __restrict__ Br, const bf16* __restrict__ Cr, const bf16* __restrict__ xup,
  const float* __restrict__ dtb, const float* __restrict__ lamb, const float* __restrict__ A_log,
  bf16* __restrict__ ypr, bf16* __restrict__ hfin, float* __restrict__ dcb, float* __restrict__ csb)
{
  __shared__ __align__(16) float Bsh[129*66];
  __shared__ __align__(16) float Csh[8*66];
  __shared__ __align__(16) float Fsh[8*133*4];
  __shared__ float dt_l[128], lam_l[128], cs_l[128], gco[129];
  int h = blockIdx.x, c = blockIdx.y;
  int g = h >> 2;
  int tid = threadIdx.x;
  int l0 = c * TCH;
  float Ah = -__expf(A_log[g]);
  float dt_prev = (c > 0) ? dtb[(l0-1)*4 + g] : 0.f;
  for (int e = tid; e < 129*64; e += 256) {
    int jj = e >> 6, col = e & 63;
    int l = l0 - 1 + jj;
    Bsh[jj*66 + col] = (l >= 0) ? bf2f(Br[((size_t)l*4+g)*64 + col]) : 0.f;
  }
  if (tid < 128) {
    dt_l[tid]  = dtb[(l0+tid)*4+g];
    lam_l[tid] = lamb[(l0+tid)*4+g];
  }
  __syncthreads();
  if (tid < 128) cs_l[tid] = dt_l[tid] * Ah;
  __syncthreads();
  for (int off = 1; off < 128; off <<= 1) {
    float add = 0.f;
    if (tid < 128 && tid >= off) add = cs_l[tid - off];
    __syncthreads();
    if (tid < 128) cs_l[tid] += add;
    __syncthreads();
  }
  if (tid == 0) dcb[c*16+h] = __expf(cs_l[127]);
  if ((h & 3) == 0 && tid < 128) csb[(c*4+g)*128 + tid] = cs_l[tid];
  __syncthreads();
  const bf16* xg = xup + ((size_t)(l0 - 1) * 16 + h) * 128;  // row jj stride 2048 elems
  int jjstart = (c == 0) ? 1 : 0;
  for (int tile = 0; tile < 16; tile++) {
    int t0 = tile * 8;
    int jjmax = t0 + 8;
    for (int e = tid; e < 8*64; e += 256) {
      int r = e >> 6, col = e & 63;
      Csh[r*66+col] = bf2f(Cr[((size_t)(l0+t0+r)*4+g)*64 + col]);
    }
    __syncthreads();
    int total = 8 * (jjmax + 1);
    for (int e = tid; e < total; e += 256) {
      int til = e / (jjmax+1);
      int jj = e - til*(jjmax+1);
      int t = t0 + til;
      float coef = 0.f;
      float cst = cs_l[t];
      if (jj >= 1 && jj <= t+1) coef += lam_l[jj-1]*dt_l[jj-1]*__expf(cst - cs_l[jj-1]);
      if (jj <= t) {
        float dtx = (jj >= 1) ? dt_l[jj-1] : dt_prev;
        coef += (1.f - lam_l[jj]) * dtx * __expf(cst - cs_l[jj]);
      }
      float4 f4 = make_float4(0.f,0.f,0.f,0.f);
      if (coef != 0.f) {
        const float2* B2 = (const float2*)&Bsh[jj*66];
        const float2* C2 = (const float2*)&Csh[til*66];
        float cb00=0,cb01=0,cb10=0,cb11=0;
        #pragma unroll
        for (int n=0;n<32;n++){
          float2 cc = C2[n]; float2 bb = B2[n];
          cb00 += cc.x*bb.x; cb01 += cc.x*bb.y;
          cb10 += cc.y*bb.x; cb11 += cc.y*bb.y;
        }
        f4 = make_float4(coef*cb00, coef*cb01, coef*cb10, coef*cb11);
      }
      ((float4*)Fsh)[til*133 + jj] = f4;
    }
    __syncthreads();
    {
      int til = tid >> 5, pg = tid & 31;
      float a0=0,a1=0,a2=0,a3=0;
      const float4* F4 = ((const float4*)Fsh) + til*133;
      #pragma unroll 4
      for (int jj = jjstart; jj <= jjmax; jj++) {
        float4 f = F4[jj];
        float4 x = ldb4(xg + (size_t)jj*2048 + 4*pg);
        a0 += f.x*x.x + f.y*x.y;
        a1 += f.z*x.x + f.w*x.y;
        a2 += f.x*x.z + f.y*x.w;
        a3 += f.z*x.z + f.w*x.w;
      }
      bf16* yp = ypr + ((size_t)(l0+t0+til)*16 + h)*128 + 4*pg;
      stb4(yp, make_float4(a0,a1,a2,a3));
    }
    __syncthreads();
  }
  // h_final coefficients
  if (tid < 129) {
    int jj = tid;
    float gc = 0.f;
    float cst = cs_l[127];
    if (jj >= 1) gc += lam_l[jj-1]*dt_l[jj-1]*__expf(cst - cs_l[jj-1]);
    if (jj <= 127) {
      float dtx = (jj >= 1) ? dt_l[jj-1] : dt_prev;
      gc += (1.f - lam_l[jj]) * dtx * __expf(cst - cs_l[jj]);
    }
    gco[jj] = gc;
  }
  __syncthreads();
  {
    int n = tid >> 3, pg = tid & 7;
    float acc[8] = {};
    for (int jj = jjstart; jj <= 128; jj++) {
      float gcv = gco[jj];
      float2 b2 = *(const float2*)&Bsh[jj*66 + n*2];
      float bx = gcv*b2.x, by = gcv*b2.y;
      const bf16* xr = xg + (size_t)jj*2048 + 16*pg;
      #pragma unroll
      for (int i=0;i<4;i++){
        float4 x4 = ldb4(xr + 4*i);
        acc[2*i]   += bx*x4.x + by*x4.y;
        acc[2*i+1] += bx*x4.z + by*x4.w;
      }
    }
    bf16* hp = hfin + (((size_t)c*16+h)*32 + n)*64 + pg*8;
    stb4(hp,   make_float4(acc[0],acc[1],acc[2],acc[3]));
    stb4(hp+4, make_float4(acc[4],acc[5],acc[6],acc[7]));
  }
}

// ---------------- K7: inter-chunk scan ----------------
__global__ void k7_scan(const bf16* __restrict__ hfin, const float* __restrict__ dcb, bf16* __restrict__ hstb)
{
  int h = blockIdx.x, tid = threadIdx.x;
  float carry[8] = {};
  for (int c = 0; c < NCHUNK; c++) {
    float dc = dcb[c*16+h];
    size_t base = ((size_t)c*16+h)*2048;
    #pragma unroll
    for (int i=0;i<8;i++){
      int e = tid + i*256;
      hstb[base+e] = f2bf(carry[i]);
      carry[i] = carry[i]*dc + bf2f(hfin[base+e]);
    }
  }
}

// ---------------- K8a: ypr += exp(cs[t]) * C[t] . h_state ----------------
__global__ void __launch_bounds__(256) k8a_yoff(const bf16* __restrict__ Cr, const bf16* __restrict__ hstb,
                                                const float* __restrict__ csb, bf16* __restrict__ ypr)
{
  __shared__ __align__(16) float Csh[128*66];
  __shared__ __align__(16) float hs[2048];
  __shared__ float cse[128];
  int h = blockIdx.x, c = blockIdx.y;
  int g = h >> 2;
  int tid = threadIdx.x;
  int l0 = c*TCH;
  for (int e=tid;e<128*64;e+=256){ int r=e>>6, col=e&63; Csh[r*66+col] = bf2f(Cr[((size_t)(l0+r)*4+g)*64+col]); }
  for (int e=tid;e<2048;e+=256) hs[e] = bf2f(hstb[((size_t)c*16+h)*2048 + e]);
  if (tid < 128) cse[tid] = __expf(csb[(c*4+g)*128 + tid]);
  __syncthreads();
  int t = tid >> 1, half = tid & 1;
  const float2* C2 = (const float2*)&Csh[t*66];
  float acc[64] = {};
  for (int n=0;n<32;n++){
    float2 c2 = C2[n];
    const float4* h4 = (const float4*)&hs[n*64 + half*32];
    #pragma unroll
    for (int i=0;i<8;i++){
      float4 x4 = h4[i];
      acc[i*8+0] += c2.x*x4.x; acc[i*8+1] += c2.y*x4.x;
      acc[i*8+2] += c2.x*x4.y; acc[i*8+3] += c2.y*x4.y;
      acc[i*8+4] += c2.x*x4.z; acc[i*8+5] += c2.y*x4.z;
      acc[i*8+6] += c2.x*x4.w; acc[i*8+7] += c2.y*x4.w;
    }
  }
  float scl = cse[t];
  bf16* yp = ypr + ((size_t)(l0+t)*16 + h)*128 + half*64;
  #pragma unroll
  for (int i=0;i<16;i++){
    float4 v = ldb4(yp + 4*i);
    v.x += scl*acc[i*4+0]; v.y += scl*acc[i*4+1]; v.z += scl*acc[i*4+2]; v.w += scl*acc[i*4+3];
    stb4(yp + 4*i, v);
  }
}

// ---- K8b: ydown + D*silu(x), * silu(z); writes y2 into upper-half slots of ypr rows ----
__global__ void k8b_ydown(bf16* __restrict__ ypr, const float* __restrict__ Wyd,
                          const bf16* __restrict__ proj, const float* __restrict__ Dp)
{
  __shared__ __align__(16) float wsh[128*64];
  __shared__ float ysh[2048];
  int l = blockIdx.x, tid = threadIdx.x;
  for (int e=tid;e<8192;e+=256) wsh[e] = Wyd[e];
  for (int e=tid;e<2048;e+=256) ysh[e] = bf2f(ypr[(size_t)l*2048 + e]);
  __syncthreads();
  int h = tid >> 4, q0 = (tid & 15) * 4;
  float acc[4] = {};
  for (int k=0;k<128;k++){
    float yv = ysh[h*128 + k];
    float4 w = *(const float4*)&wsh[k*64 + q0];
    acc[0]+=yv*w.x; acc[1]+=yv*w.y; acc[2]+=yv*w.z; acc[3]+=yv*w.w;
  }
  float dv = Dp[h];
  const bf16* pr = proj + (size_t)l*DPROJ;
  float4 xq = ldb4(pr + 1024 + h*64 + q0);
  float4 zq = ldb4(pr + h*64 + q0);
  float xv[4] = {xq.x,xq.y,xq.z,xq.w};
  float zv[4] = {zq.x,zq.y,zq.z,zq.w};
  float out[4];
  #pragma unroll
  for (int i=0;i<4;i++){
    float xs = xv[i]/(1.f+__expf(-xv[i]));
    float zs = zv[i]/(1.f+__expf(-zv[i]));
    out[i] = (acc[i] + dv*xs) * zs;
  }
  stb4(ypr + (size_t)l*2048 + h*128 + 64 + q0, make_float4(out[0],out[1],out[2],out[3]));
}

// ---------------- GEMM_OUT: out = y2 @ W_out (fp32 out), y2 from interleaved ypr slots ----------
__global__ void __launch_bounds__(256) gemm_out(const bf16* __restrict__ Yp, const float* __restrict__ B,
                                                float* __restrict__ C, int M, int N, int K)
{
  const int BM=64, BN=64, BK=16;
  __shared__ __align__(16) float As[BK*68];
  __shared__ __align__(16) float Bs[BK*68];
  int col0 = blockIdx.x*BN, row0 = blockIdx.y*BM;
  int tid = threadIdx.x;
  int tr = tid >> 4, tc = tid & 15;
  float acc[4][4] = {};
  for (int k0 = 0; k0 < K; k0 += BK) {
    for (int e = tid; e < BM*BK; e += 256) {
      int r = e >> 4, kk = e & 15;
      int kg = k0 + kk;
      As[kk*68 + r] = bf2f(Yp[(size_t)(row0+r)*2048 + ((kg>>6)*128) + 64 + (kg & 63)]);
    }
    for (int e = tid; e < BK*BN; e += 256) {
      int kk = e >> 6, cc = e & 63;
      Bs[kk*68 + cc] = B[(size_t)(k0+kk)*N + col0 + cc];
    }
    __syncthreads();
    #pragma unroll
    for (int kk = 0; kk < BK; kk++) {
      float4 a4 = *(const float4*)&As[kk*68 + tr*4];
      float4 b4 = *(const float4*)&Bs[kk*68 + tc*4];
      float av[4] = {a4.x,a4.y,a4.z,a4.w};
      float bv[4] = {b4.x,b4.y,b4.z,b4.w};
      #pragma unroll
      for (int m=0;m<4;m++)
        #pragma unroll
        for (int n=0;n<4;n++) acc[m][n] += av[m]*bv[n];
    }
    __syncthreads();
  }
  #pragma unroll
  for (int m=0;m<4;m++){
    int gr = row0 + tr*4 + m;
    #pragma unroll
    for (int n=0;n<4;n++){
      C[(size_t)gr*N + col0 + tc*4 + n] = acc[m][n];
    }
  }
}

extern "C" void kernel_launch(void* const* d_in, const int* in_sizes, int n_in,
                              void* d_out, int out_size, void* d_ws, size_t ws_size,
                              hipStream_t stream) {
  const float* u       = (const float*)d_in[0];
  const float* W_in    = (const float*)d_in[1];
  const float* b_in    = (const float*)d_in[2];
  const float* W_xup   = (const float*)d_in[3];
  const float* W_ydown = (const float*)d_in[4];
  const float* A_log   = (const float*)d_in[5];
  const float* theta_l = (const float*)d_in[6];
  const float* D_p     = (const float*)d_in[7];
  const float* wB      = (const float*)d_in[8];
  const float* wC      = (const float*)d_in[9];
  const float* biasB   = (const float*)d_in[10];
  const float* biasC   = (const float*)d_in[11];
  const float* W_out   = (const float*)d_in[12];
  float* out = (float*)d_out;

  char* w = (char*)d_ws;
  // total footprint: ~31.7 MB
  bf16*  proj  = (bf16*)(w);                       // 2048*2568 bf16 = 10,518,528 B
  float* dlraw = (float*)(w + 10518528);           // 2048*8 f32     =     65,536 B
  float* dtb   = (float*)(w + 10584064);           // 2048*4 f32     =     32,768 B
  float* lamb  = (float*)(w + 10616832);           //                      32,768 B
  float* csdt  = (float*)(w + 10649600);           //                      32,768 B
  bf16*  Brb   = (bf16*)(w + 10682368);            // 2048*256 bf16  =  1,048,576 B
  bf16*  Crb   = (bf16*)(w + 11730944);            //                   1,048,576 B
  bf16*  xupb  = (bf16*)(w + 12779520);            // 2048*2048 bf16 =  8,388,608 B
  bf16*  hfin  = (bf16*)(w + 21168128);            // 16*16*2048 bf16=  1,048,576 B
  bf16*  hstb  = (bf16*)(w + 22216704);            //                   1,048,576 B
  float* dcb   = (float*)(w + 23265280);           // 256 f32        =      1,024 B
  float* csb   = (float*)(w + 23266304);           // 8192 f32       =     32,768 B
  bf16*  ypr   = (bf16*)(w + 23299072);            // 2048*2048 bf16 =  8,388,608 B

  gemm1<<<dim3(41,32),256,0,stream>>>(u, W_in, b_in, proj, dlraw, 2048, DPROJ, 512);
  k23<<<1,256,0,stream>>>(dlraw, dtb, lamb, csdt);
  k4_rmsrope<<<2048,256,0,stream>>>(proj, wB, wC, biasB, biasC, theta_l, csdt, Brb, Crb);
  k5_xup<<<2048,256,0,stream>>>(proj, W_xup, xupb);
  k6_scan<<<dim3(16,16),256,0,stream>>>(Brb, Crb, xupb, dtb, lamb, A_log, ypr, hfin, dcb, csb);
  k7_scan<<<16,256,0,stream>>>(hfin, dcb, hstb);
  k8a_yoff<<<dim3(16,16),256,0,stream>>>(Crb, hstb, csb, ypr);
  k8b_ydown<<<2048,256,0,stream>>>(ypr, W_ydown, proj, D_p);
  gemm_out<<<dim3(8,32),256,0,stream>>>(ypr, W_out, out, 2048, 512, 1024);
}

// Round 4
// 317.222 us; speedup vs baseline: 1.7458x; 1.7458x over previous
//
#include <hip/hip_runtime.h>
#include <hip/hip_bf16.h>

typedef __hip_bfloat16 bf16;
typedef __bf16 bfv8 __attribute__((ext_vector_type(8)));
typedef float fv4 __attribute__((ext_vector_type(4)));

__device__ __forceinline__ float bf2f(bf16 x){ return __bfloat162float(x); }
__device__ __forceinline__ bf16 f2bf(float x){ return __float2bfloat16(x); }
__device__ __forceinline__ float blo(unsigned u){ return __uint_as_float(u<<16); }
__device__ __forceinline__ float bhi(unsigned u){ return __uint_as_float(u & 0xffff0000u); }
struct __align__(8) bf4v { bf16 x,y,z,w; };
struct __align__(16) bf8s { ushort u[8]; };
__device__ __forceinline__ float4 ldb4(const bf16* p){
  ushort4 u = *(const ushort4*)p;
  float4 r;
  r.x = __uint_as_float(((unsigned)u.x)<<16);
  r.y = __uint_as_float(((unsigned)u.y)<<16);
  r.z = __uint_as_float(((unsigned)u.z)<<16);
  r.w = __uint_as_float(((unsigned)u.w)<<16);
  return r;
}
__device__ __forceinline__ void stb4(bf16* p, float4 v){
  bf4v t; t.x=f2bf(v.x); t.y=f2bf(v.y); t.z=f2bf(v.z); t.w=f2bf(v.w);
  *(bf4v*)p = t;
}

#define L_SEQ 2048
#define DPROJ 2568
#define NCHUNK 16
#define TCH 128

// ---------------- tcastT: out[C][R] (bf16, rows padded to Cpad with zeros) = in[R][C]^T ---------
__global__ void tcastT(const float* __restrict__ in, bf16* __restrict__ out, int R, int C, int Cpad)
{
  __shared__ float t[32][33];
  int c0 = blockIdx.x*32, r0 = blockIdx.y*32;
  int tx = threadIdx.x & 31, ty = threadIdx.x >> 5;   // ty 0..7
  for (int i=0;i<32;i+=8){
    int r = r0+i+ty, cc = c0+tx;
    t[i+ty][tx] = (r<R && cc<C) ? in[(size_t)r*C+cc] : 0.f;
  }
  __syncthreads();
  for (int i=0;i<32;i+=8){
    int cc = c0+i+ty, r = r0+tx;
    if (cc<Cpad && r<R) out[(size_t)cc*R + r] = f2bf(t[tx][i+ty]);
  }
}

// ---------------- GEMM1 (MFMA): proj(2048x2568 bf16) = u(fp32) @ W_in + b_in; side fp32 --------
__global__ void __launch_bounds__(256) gemm1_mfma(const float* __restrict__ A, const bf16* __restrict__ BT,
                                                  const float* __restrict__ bias, bf16* __restrict__ C,
                                                  float* __restrict__ side)
{
  const int K = 512;
  __shared__ __align__(16) bf16 As[128*40];
  __shared__ __align__(16) bf16 Bs[64*40];
  int tid = threadIdx.x;
  int col0 = blockIdx.x*64, row0 = blockIdx.y*128;
  int wid = tid>>6, lane = tid&63;
  int wm = (wid&1)*64, wn = (wid>>1)*32;
  int lm = lane&15, lq = lane>>4;
  fv4 acc[4][2] = {};
  for (int k0=0;k0<K;k0+=32){
    #pragma unroll
    for (int i=0;i<4;i++){
      int m = i*32 + (tid>>3);
      int k4 = (tid&7)*4;
      float4 v = *(const float4*)&A[(size_t)(row0+m)*K + k0 + k4];
      bf4v b; b.x=f2bf(v.x); b.y=f2bf(v.y); b.z=f2bf(v.z); b.w=f2bf(v.w);
      *(bf4v*)&As[m*40+k4] = b;
    }
    {
      int n = tid>>2, k8 = (tid&3)*8;
      *(bf8s*)&Bs[n*40+k8] = *(const bf8s*)&BT[(size_t)(col0+n)*K + k0 + k8];
    }
    __syncthreads();
    bfv8 af[4], bfr[2];
    #pragma unroll
    for (int mf=0;mf<4;mf++) af[mf] = *(const bfv8*)&As[(wm+mf*16+lm)*40 + lq*8];
    #pragma unroll
    for (int nf=0;nf<2;nf++) bfr[nf] = *(const bfv8*)&Bs[(wn+nf*16+lm)*40 + lq*8];
    #pragma unroll
    for (int mf=0;mf<4;mf++)
      #pragma unroll
      for (int nf=0;nf<2;nf++)
        acc[mf][nf] = __builtin_amdgcn_mfma_f32_16x16x32_bf16(af[mf], bfr[nf], acc[mf][nf], 0,0,0);
    __syncthreads();
  }
  #pragma unroll
  for (int mf=0;mf<4;mf++){
    #pragma unroll
    for (int nf=0;nf<2;nf++){
      int gcol = col0 + wn + nf*16 + lm;
      if (gcol < DPROJ){
        float bia = bias[gcol];
        #pragma unroll
        for (int r=0;r<4;r++){
          int grow = row0 + wm + mf*16 + lq*4 + r;
          float v = acc[mf][nf][r] + bia;
          C[(size_t)grow*DPROJ + gcol] = f2bf(v);
          if (gcol >= 2560) side[grow*8 + (gcol-2560)] = v;
        }
      }
    }
  }
}

// ---------------- GEMM_OUT (MFMA): out(2048x512 fp32) = y2(interleaved ypr bf16) @ W_out --------
__global__ void __launch_bounds__(256) gemmo_mfma(const bf16* __restrict__ Yp, const bf16* __restrict__ BT,
                                                  float* __restrict__ C)
{
  const int K = 1024;
  __shared__ __align__(16) bf16 As[64*40];
  __shared__ __align__(16) bf16 Bs[64*40];
  int tid = threadIdx.x;
  int col0 = blockIdx.x*64, row0 = blockIdx.y*64;
  int wid = tid>>6, lane = tid&63;
  int wm = (wid&1)*32, wn = (wid>>1)*32;
  int lm = lane&15, lq = lane>>4;
  fv4 acc[2][2] = {};
  for (int k0=0;k0<K;k0+=32){
    {
      int m = tid>>2, k8 = (tid&3)*8;
      int kg = k0 + k8;
      *(bf8s*)&As[m*40+k8] = *(const bf8s*)&Yp[(size_t)(row0+m)*2048 + ((kg>>6)*128) + 64 + (kg&63)];
    }
    {
      int n = tid>>2, k8 = (tid&3)*8;
      *(bf8s*)&Bs[n*40+k8] = *(const bf8s*)&BT[(size_t)(col0+n)*K + k0 + k8];
    }
    __syncthreads();
    bfv8 af[2], bfr[2];
    #pragma unroll
    for (int mf=0;mf<2;mf++) af[mf] = *(const bfv8*)&As[(wm+mf*16+lm)*40 + lq*8];
    #pragma unroll
    for (int nf=0;nf<2;nf++) bfr[nf] = *(const bfv8*)&Bs[(wn+nf*16+lm)*40 + lq*8];
    #pragma unroll
    for (int mf=0;mf<2;mf++)
      #pragma unroll
      for (int nf=0;nf<2;nf++)
        acc[mf][nf] = __builtin_amdgcn_mfma_f32_16x16x32_bf16(af[mf], bfr[nf], acc[mf][nf], 0,0,0);
    __syncthreads();
  }
  #pragma unroll
  for (int mf=0;mf<2;mf++)
    #pragma unroll
    for (int nf=0;nf<2;nf++){
      int gcol = col0 + wn + nf*16 + lm;
      #pragma unroll
      for (int r=0;r<4;r++){
        int grow = row0 + wm + mf*16 + lq*4 + r;
        C[(size_t)grow*512 + gcol] = acc[mf][nf][r];
      }
    }
}

// ---------------- K23: dt = softplus, lam = sigmoid, csdt = cumsum_l(dt) (single block) ---------
__global__ void k23(const float* __restrict__ dlraw, float* __restrict__ dtb,
                    float* __restrict__ lamb, float* __restrict__ csdt)
{
  __shared__ float dts[L_SEQ*4];
  __shared__ float segs[4][64];
  int tid = threadIdx.x;
  int g = tid & 3, seg = tid >> 2;
  for (int i = 0; i < 32; i++){
    int l = seg*32 + i;
    float dr = dlraw[l*8 + g];
    float lr = dlraw[l*8 + 4 + g];
    float dt = (dr > 15.f) ? dr : log1pf(__expf(dr));
    dts[l*4+g] = dt;
    dtb[l*4+g] = dt;
    lamb[l*4+g] = 1.f/(1.f+__expf(-lr));
  }
  __syncthreads();
  float s = 0.f;
  for (int i=0;i<32;i++) s += dts[(seg*32+i)*4 + g];
  segs[g][seg] = s;
  __syncthreads();
  if (tid < 4) { float run = 0.f; for (int q=0;q<64;q++){ float t = segs[tid][q]; segs[tid][q] = run; run += t; } }
  __syncthreads();
  float run = segs[g][seg];
  for (int i=0;i<32;i++){ int l = seg*32+i; run += dts[l*4+g]; csdt[l*4+g] = run; }
}

// ---------------- K4: rmsnorm + bias + RoPE -> Br, Cr (bf16, layout [l][g][n*2+r]) --------------
__global__ void k4_rmsrope(const bf16* __restrict__ proj, const float* __restrict__ wB, const float* __restrict__ wC,
                           const float* __restrict__ biasB, const float* __restrict__ biasC,
                           const float* __restrict__ theta_log, const float* __restrict__ csdt,
                           bf16* __restrict__ Br, bf16* __restrict__ Cr)
{
  int l = blockIdx.x;
  int tid = threadIdx.x;
  int g = tid >> 6, idx = tid & 63;   // one wave per group
  const bf16* pr = proj + (size_t)l*DPROJ;
  float bv = bf2f(pr[2048 + g*64 + idx]);
  float cv = bf2f(pr[2304 + g*64 + idx]);
  float sb = bv*bv, sc = cv*cv;
  #pragma unroll
  for (int off=32; off; off>>=1){ sb += __shfl_xor(sb, off); sc += __shfl_xor(sc, off); }
  float rb = rsqrtf(sb*(1.f/64.f) + 1e-5f);
  float rc = rsqrtf(sc*(1.f/64.f) + 1e-5f);
  float bm = bv*rb*wB[idx] + biasB[g*64+idx];
  float cm = cv*rc*wC[idx] + biasC[g*64+idx];
  int k = idx >> 2;
  float ang = csdt[l*4+g] * __expf(theta_log[g*16+k]);
  float ca = cosf(ang), sa = sinf(ang);
  float bp = __shfl_xor(bm, 2);
  float cp = __shfl_xor(cm, 2);
  bool is_im = (idx >> 1) & 1;
  float bo = is_im ? (bp*sa + bm*ca) : (bm*ca - bp*sa);
  float co = is_im ? (cp*sa + cm*ca) : (cm*ca - cp*sa);
  Br[((size_t)l*4+g)*64 + idx] = f2bf(bo);
  Cr[((size_t)l*4+g)*64 + idx] = f2bf(co);
}

// ---------------- K5: x_up[l][h][p*2+r] = silu(x) @ W_xup ----------------
__global__ void k5_xup(const bf16* __restrict__ proj, const float* __restrict__ Wx, bf16* __restrict__ xup)
{
  __shared__ __align__(16) float wsm[64*128];
  __shared__ float xs[1024];
  int l = blockIdx.x, tid = threadIdx.x;
  for (int e=tid;e<8192;e+=256) wsm[e] = Wx[e];
  for (int e=tid;e<1024;e+=256){ float v = bf2f(proj[(size_t)l*DPROJ+1024+e]); xs[e] = v/(1.f+__expf(-v)); }
  __syncthreads();
  int h = tid>>4, prb = (tid&15)*8;
  float acc[8] = {};
  for (int k=0;k<64;k++){
    float xv = xs[h*64+k];
    const float4* w4 = (const float4*)&wsm[k*128 + prb];
    float4 a = w4[0], b = w4[1];
    acc[0]+=xv*a.x; acc[1]+=xv*a.y; acc[2]+=xv*a.z; acc[3]+=xv*a.w;
    acc[4]+=xv*b.x; acc[5]+=xv*b.y; acc[6]+=xv*b.z; acc[7]+=xv*b.w;
  }
  bf16* o = xup + ((size_t)l*16+h)*128 + prb;
  stb4(o,   make_float4(acc[0],acc[1],acc[2],acc[3]));
  stb4(o+4, make_float4(acc[4],acc[5],acc[6],acc[7]));
}

// ---------------- K6: per (chunk,head,half): y_diag (regrouped trapezoid) + h_final -------------
__global__ void __launch_bounds__(256) k6_scan(
  const bf16* __restrict__ Br, const bf16* __restrict__ Cr, const bf16* __restrict__ xup,
  const float* __restrict__ dtb, const float* __restrict__ lamb, const float* __restrict__ A_log,
  bf16* __restrict__ ypr, bf16* __restrict__ hfin, float* __restrict__ dcb, float* __restrict__ csb)
{
  __shared__ __align__(16) bf16 Bsh[129*68];   // bf16 B rows, stride 68
  __shared__ __align__(16) bf16 xsh[129*128];  // bf16 xup rows
  __shared__ __align__(16) bf16 Fsh[8*130*4];  // bf16 F coefs (4 per entry)
  __shared__ float Csh[8*66];
  __shared__ float dt_l[128], lam_l[128], cs_l[128], gco[129];
  int h = blockIdx.x, c = blockIdx.y, half = blockIdx.z;
  int g = h >> 2;
  int tid = threadIdx.x;
  int l0 = c * TCH;
  int tbase = half*64;
  int mx = half ? 129 : 65;  // B/x rows needed
  float Ah = -__expf(A_log[g]);
  float dt_prev = (c > 0) ? dtb[(l0-1)*4 + g] : 0.f;
  // stage B rows
  for (int e = tid; e < mx*16; e += 256) {
    int jj = e >> 4, c4 = (e & 15)*4;
    int l = l0 - 1 + jj;
    if (l >= 0) *(bf4v*)&Bsh[jj*68 + c4] = *(const bf4v*)&Br[((size_t)l*4+g)*64 + c4];
    else { bf4v z; z.x=z.y=z.z=z.w=f2bf(0.f); *(bf4v*)&Bsh[jj*68 + c4] = z; }
  }
  // stage xup rows
  for (int e = tid; e < mx*32; e += 256) {
    int jj = e >> 5, c4 = (e & 31)*4;
    int l = l0 - 1 + jj;
    if (l >= 0) *(bf4v*)&xsh[jj*128 + c4] = *(const bf4v*)&xup[((size_t)l*16+h)*128 + c4];
    else { bf4v z; z.x=z.y=z.z=z.w=f2bf(0.f); *(bf4v*)&xsh[jj*128 + c4] = z; }
  }
  if (tid < 128) {
    dt_l[tid]  = dtb[(l0+tid)*4+g];
    lam_l[tid] = lamb[(l0+tid)*4+g];
  }
  __syncthreads();
  if (tid < 128) cs_l[tid] = dt_l[tid] * Ah;
  __syncthreads();
  for (int off = 1; off < 128; off <<= 1) {
    float add = 0.f;
    if (tid < 128 && tid >= off) add = cs_l[tid - off];
    __syncthreads();
    if (tid < 128) cs_l[tid] += add;
    __syncthreads();
  }
  if (half == 1 && tid == 0) dcb[c*16+h] = __expf(cs_l[127]);
  if (half == 1 && (h & 3) == 0 && tid < 128) csb[(c*4+g)*128 + tid] = cs_l[tid];
  __syncthreads();
  int jjstart = (c == 0) ? 1 : 0;
  for (int tile = 0; tile < 8; tile++) {
    int t0 = tbase + tile * 8;
    int jjmax = t0 + 8;
    for (int e = tid; e < 8*64; e += 256) {
      int r = e >> 6, col = e & 63;
      Csh[r*66+col] = bf2f(Cr[((size_t)(l0+t0+r)*4+g)*64 + col]);
    }
    __syncthreads();
    int total = 8 * (jjmax + 1);
    for (int e = tid; e < total; e += 256) {
      int til = e / (jjmax+1);
      int jj = e - til*(jjmax+1);
      int t = t0 + til;
      float coef = 0.f;
      float cst = cs_l[t];
      if (jj >= 1 && jj <= t+1) coef += lam_l[jj-1]*dt_l[jj-1]*__expf(cst - cs_l[jj-1]);
      if (jj <= t) {
        float dtx = (jj >= 1) ? dt_l[jj-1] : dt_prev;
        coef += (1.f - lam_l[jj]) * dtx * __expf(cst - cs_l[jj]);
      }
      float cb00=0,cb01=0,cb10=0,cb11=0;
      if (coef != 0.f) {
        const unsigned* B2 = (const unsigned*)&Bsh[jj*68];
        const float2* C2 = (const float2*)&Csh[til*66];
        #pragma unroll
        for (int n=0;n<32;n++){
          unsigned bb = B2[n];
          float b0 = blo(bb), b1 = bhi(bb);
          float2 cc = C2[n];
          cb00 += cc.x*b0; cb01 += cc.x*b1;
          cb10 += cc.y*b0; cb11 += cc.y*b1;
        }
      }
      bf4v f; f.x=f2bf(coef*cb00); f.y=f2bf(coef*cb01); f.z=f2bf(coef*cb10); f.w=f2bf(coef*cb11);
      *(bf4v*)&Fsh[(til*130 + jj)*4] = f;
    }
    __syncthreads();
    {
      int til = tid >> 5, pg = tid & 31;
      int t = t0 + til;
      float a0=0,a1=0,a2=0,a3=0;
      for (int jj = jjstart; jj <= jjmax; jj++) {
        uint2 fu = *(const uint2*)&Fsh[(til*130 + jj)*4];
        float fx = blo(fu.x), fy = bhi(fu.x), fz = blo(fu.y), fw = bhi(fu.y);
        uint2 xu = *(const uint2*)&xsh[jj*128 + 4*pg];
        float x0 = blo(xu.x), x1 = bhi(xu.x), x2 = blo(xu.y), x3 = bhi(xu.y);
        a0 += fx*x0 + fy*x1;
        a1 += fz*x0 + fw*x1;
        a2 += fx*x2 + fy*x3;
        a3 += fz*x2 + fw*x3;
      }
      bf16* yp = ypr + ((size_t)(l0+t)*16 + h)*128 + 4*pg;
      stb4(yp, make_float4(a0,a1,a2,a3));
    }
    __syncthreads();
  }
  if (half == 1) {
    // h_final coefficients
    if (tid < 129) {
      int jj = tid;
      float gc = 0.f;
      float cst = cs_l[127];
      if (jj >= 1) gc += lam_l[jj-1]*dt_l[jj-1]*__expf(cst - cs_l[jj-1]);
      if (jj <= 127) {
        float dtx = (jj >= 1) ? dt_l[jj-1] : dt_prev;
        gc += (1.f - lam_l[jj]) * dtx * __expf(cst - cs_l[jj]);
      }
      gco[jj] = gc;
    }
    __syncthreads();
    {
      int n = tid >> 3, pg = tid & 7;
      float acc[8] = {};
      for (int jj = jjstart; jj <= 128; jj++) {
        float gcv = gco[jj];
        unsigned bb = *(const unsigned*)&Bsh[jj*68 + n*2];
        float bx = gcv*blo(bb), by = gcv*bhi(bb);
        const uint2* xr = (const uint2*)&xsh[jj*128 + 16*pg];
        #pragma unroll
        for (int i=0;i<4;i++){
          uint2 xu = xr[i];
          float x0 = blo(xu.x), x1 = bhi(xu.x), x2 = blo(xu.y), x3 = bhi(xu.y);
          acc[2*i]   += bx*x0 + by*x1;
          acc[2*i+1] += bx*x2 + by*x3;
        }
      }
      bf16* hp = hfin + (((size_t)c*16+h)*32 + n)*64 + pg*8;
      stb4(hp,   make_float4(acc[0],acc[1],acc[2],acc[3]));
      stb4(hp+4, make_float4(acc[4],acc[5],acc[6],acc[7]));
    }
  }
}

// ---------------- K7: inter-chunk scan ----------------
__global__ void k7_scan(const bf16* __restrict__ hfin, const float* __restrict__ dcb, bf16* __restrict__ hstb)
{
  int h = blockIdx.x, tid = threadIdx.x;
  float carry[8] = {};
  for (int c = 0; c < NCHUNK; c++) {
    float dc = dcb[c*16+h];
    size_t base = ((size_t)c*16+h)*2048;
    #pragma unroll
    for (int i=0;i<8;i++){
      int e = tid + i*256;
      hstb[base+e] = f2bf(carry[i]);
      carry[i] = carry[i]*dc + bf2f(hfin[base+e]);
    }
  }
}

// ---------------- K8a: ypr += exp(cs[t]) * C[t] . h_state ----------------
__global__ void __launch_bounds__(256) k8a_yoff(const bf16* __restrict__ Cr, const bf16* __restrict__ hstb,
                                                const float* __restrict__ csb, bf16* __restrict__ ypr)
{
  __shared__ __align__(16) float Csh[128*66];
  __shared__ __align__(16) float hs[2048];
  __shared__ float cse[128];
  int h = blockIdx.x, c = blockIdx.y;
  int g = h >> 2;
  int tid = threadIdx.x;
  int l0 = c*TCH;
  for (int e=tid;e<128*64;e+=256){ int r=e>>6, col=e&63; Csh[r*66+col] = bf2f(Cr[((size_t)(l0+r)*4+g)*64+col]); }
  for (int e=tid;e<2048;e+=256) hs[e] = bf2f(hstb[((size_t)c*16+h)*2048 + e]);
  if (tid < 128) cse[tid] = __expf(csb[(c*4+g)*128 + tid]);
  __syncthreads();
  int t = tid >> 1, half = tid & 1;
  const float2* C2 = (const float2*)&Csh[t*66];
  float acc[64] = {};
  for (int n=0;n<32;n++){
    float2 c2 = C2[n];
    const float4* h4 = (const float4*)&hs[n*64 + half*32];
    #pragma unroll
    for (int i=0;i<8;i++){
      float4 x4 = h4[i];
      acc[i*8+0] += c2.x*x4.x; acc[i*8+1] += c2.y*x4.x;
      acc[i*8+2] += c2.x*x4.y; acc[i*8+3] += c2.y*x4.y;
      acc[i*8+4] += c2.x*x4.z; acc[i*8+5] += c2.y*x4.z;
      acc[i*8+6] += c2.x*x4.w; acc[i*8+7] += c2.y*x4.w;
    }
  }
  float scl = cse[t];
  bf16* yp = ypr + ((size_t)(l0+t)*16 + h)*128 + half*64;
  #pragma unroll
  for (int i=0;i<16;i++){
    float4 v = ldb4(yp + 4*i);
    v.x += scl*acc[i*4+0]; v.y += scl*acc[i*4+1]; v.z += scl*acc[i*4+2]; v.w += scl*acc[i*4+3];
    stb4(yp + 4*i, v);
  }
}

// ---- K8b: ydown + D*silu(x), * silu(z); writes y2 into upper-half slots of ypr rows ----
__global__ void k8b_ydown(bf16* __restrict__ ypr, const float* __restrict__ Wyd,
                          const bf16* __restrict__ proj, const float* __restrict__ Dp)
{
  __shared__ __align__(16) float wsh[128*64];
  __shared__ float ysh[2048];
  int l = blockIdx.x, tid = threadIdx.x;
  for (int e=tid;e<8192;e+=256) wsh[e] = Wyd[e];
  for (int e=tid;e<2048;e+=256) ysh[e] = bf2f(ypr[(size_t)l*2048 + e]);
  __syncthreads();
  int h = tid >> 4, q0 = (tid & 15) * 4;
  float acc[4] = {};
  for (int k=0;k<128;k++){
    float yv = ysh[h*128 + k];
    float4 w = *(const float4*)&wsh[k*64 + q0];
    acc[0]+=yv*w.x; acc[1]+=yv*w.y; acc[2]+=yv*w.z; acc[3]+=yv*w.w;
  }
  float dv = Dp[h];
  const bf16* pr = proj + (size_t)l*DPROJ;
  float4 xq = ldb4(pr + 1024 + h*64 + q0);
  float4 zq = ldb4(pr + h*64 + q0);
  float xv[4] = {xq.x,xq.y,xq.z,xq.w};
  float zv[4] = {zq.x,zq.y,zq.z,zq.w};
  float out[4];
  #pragma unroll
  for (int i=0;i<4;i++){
    float xs = xv[i]/(1.f+__expf(-xv[i]));
    float zs = zv[i]/(1.f+__expf(-zv[i]));
    out[i] = (acc[i] + dv*xs) * zs;
  }
  stb4(ypr + (size_t)l*2048 + h*128 + 64 + q0, make_float4(out[0],out[1],out[2],out[3]));
}

extern "C" void kernel_launch(void* const* d_in, const int* in_sizes, int n_in,
                              void* d_out, int out_size, void* d_ws, size_t ws_size,
                              hipStream_t stream) {
  const float* u       = (const float*)d_in[0];
  const float* W_in    = (const float*)d_in[1];
  const float* b_in    = (const float*)d_in[2];
  const float* W_xup   = (const float*)d_in[3];
  const float* W_ydown = (const float*)d_in[4];
  const float* A_log   = (const float*)d_in[5];
  const float* theta_l = (const float*)d_in[6];
  const float* D_p     = (const float*)d_in[7];
  const float* wB      = (const float*)d_in[8];
  const float* wC      = (const float*)d_in[9];
  const float* biasB   = (const float*)d_in[10];
  const float* biasC   = (const float*)d_in[11];
  const float* W_out   = (const float*)d_in[12];
  float* out = (float*)d_out;

  char* w = (char*)d_ws;
  // total footprint: ~31.7 MB
  bf16*  proj  = (bf16*)(w);                       // 10,518,528 B
  float* dlraw = (float*)(w + 10518528);           //     65,536 B
  float* dtb   = (float*)(w + 10584064);           //     32,768 B
  float* lamb  = (float*)(w + 10616832);           //     32,768 B
  float* csdt  = (float*)(w + 10649600);           //     32,768 B
  bf16*  Brb   = (bf16*)(w + 10682368);            //  1,048,576 B   (aliased by WoutT after k8a)
  bf16*  Crb   = (bf16*)(w + 11730944);            //  1,048,576 B
  bf16*  xupb  = (bf16*)(w + 12779520);            //  8,388,608 B
  bf16*  hfin  = (bf16*)(w + 21168128);            //  1,048,576 B
  bf16*  hstb  = (bf16*)(w + 22216704);            //  1,048,576 B
  float* dcb   = (float*)(w + 23265280);           //      1,024 B
  float* csb   = (float*)(w + 23266304);           //     32,768 B
  bf16*  ypr   = (bf16*)(w + 23299072);            //  8,388,608 B   (aliased by WinT before k6)
  bf16*  WinT  = (bf16*)(w + 23299072);            //  2,686,976 B (2624x512), dead once k6 writes ypr
  bf16*  WoutT = (bf16*)(w + 10682368);            //  1,048,576 B (512x1024), created after k8a

  tcastT<<<dim3(82,16),256,0,stream>>>(W_in, WinT, 512, DPROJ, 2624);
  gemm1_mfma<<<dim3(41,16),256,0,stream>>>(u, WinT, b_in, proj, dlraw);
  k23<<<1,256,0,stream>>>(dlraw, dtb, lamb, csdt);
  k4_rmsrope<<<2048,256,0,stream>>>(proj, wB, wC, biasB, biasC, theta_l, csdt, Brb, Crb);
  k5_xup<<<2048,256,0,stream>>>(proj, W_xup, xupb);
  k6_scan<<<dim3(16,16,2),256,0,stream>>>(Brb, Crb, xupb, dtb, lamb, A_log, ypr, hfin, dcb, csb);
  k7_scan<<<16,256,0,stream>>>(hfin, dcb, hstb);
  k8a_yoff<<<dim3(16,16),256,0,stream>>>(Crb, hstb, csb, ypr);
  tcastT<<<dim3(16,32),256,0,stream>>>(W_out, WoutT, 1024, 512, 512);
  k8b_ydown<<<2048,256,0,stream>>>(ypr, W_ydown, proj, D_p);
  gemmo_mfma<<<dim3(8,32),256,0,stream>>>(ypr, WoutT, out);
}

// Round 5
// 278.574 us; speedup vs baseline: 1.9880x; 1.1387x over previous
//
#include <hip/hip_runtime.h>
#include <hip/hip_bf16.h>

typedef __hip_bfloat16 bf16;
typedef __bf16 bfv8 __attribute__((ext_vector_type(8)));
typedef float fv4 __attribute__((ext_vector_type(4)));

__device__ __forceinline__ float bf2f(bf16 x){ return __bfloat162float(x); }
__device__ __forceinline__ bf16 f2bf(float x){ return __float2bfloat16(x); }
__device__ __forceinline__ float blo(unsigned u){ return __uint_as_float(u<<16); }
__device__ __forceinline__ float bhi(unsigned u){ return __uint_as_float(u & 0xffff0000u); }
struct __align__(8) bf4v { bf16 x,y,z,w; };
struct __align__(16) bf8s { ushort u[8]; };
__device__ __forceinline__ float4 ldb4(const bf16* p){
  ushort4 u = *(const ushort4*)p;
  float4 r;
  r.x = __uint_as_float(((unsigned)u.x)<<16);
  r.y = __uint_as_float(((unsigned)u.y)<<16);
  r.z = __uint_as_float(((unsigned)u.z)<<16);
  r.w = __uint_as_float(((unsigned)u.w)<<16);
  return r;
}
__device__ __forceinline__ void stb4(bf16* p, float4 v){
  bf4v t; t.x=f2bf(v.x); t.y=f2bf(v.y); t.z=f2bf(v.z); t.w=f2bf(v.w);
  *(bf4v*)p = t;
}

#define L_SEQ 2048
#define DPROJ 2568
#define NCHUNK 16
#define TCH 128

// ---------------- tcastT: out[C][R] (bf16, rows padded to Cpad with zeros) = in[R][C]^T ---------
__global__ void tcastT(const float* __restrict__ in, bf16* __restrict__ out, int R, int C, int Cpad)
{
  __shared__ float t[32][33];
  int c0 = blockIdx.x*32, r0 = blockIdx.y*32;
  int tx = threadIdx.x & 31, ty = threadIdx.x >> 5;
  for (int i=0;i<32;i+=8){
    int r = r0+i+ty, cc = c0+tx;
    t[i+ty][tx] = (r<R && cc<C) ? in[(size_t)r*C+cc] : 0.f;
  }
  __syncthreads();
  for (int i=0;i<32;i+=8){
    int cc = c0+i+ty, r = r0+tx;
    if (cc<Cpad && r<R) out[(size_t)cc*R + r] = f2bf(t[tx][i+ty]);
  }
}

// ---------------- GEMM1 (MFMA): proj(2048x2568 bf16) = u(fp32) @ W_in + b_in; side fp32 --------
__global__ void __launch_bounds__(256) gemm1_mfma(const float* __restrict__ A, const bf16* __restrict__ BT,
                                                  const float* __restrict__ bias, bf16* __restrict__ C,
                                                  float* __restrict__ side)
{
  const int K = 512;
  __shared__ __align__(16) bf16 As[128*40];
  __shared__ __align__(16) bf16 Bs[64*40];
  int tid = threadIdx.x;
  int col0 = blockIdx.x*64, row0 = blockIdx.y*128;
  int wid = tid>>6, lane = tid&63;
  int wm = (wid&1)*64, wn = (wid>>1)*32;
  int lm = lane&15, lq = lane>>4;
  fv4 acc[4][2] = {};
  for (int k0=0;k0<K;k0+=32){
    #pragma unroll
    for (int i=0;i<4;i++){
      int m = i*32 + (tid>>3);
      int k4 = (tid&7)*4;
      float4 v = *(const float4*)&A[(size_t)(row0+m)*K + k0 + k4];
      bf4v b; b.x=f2bf(v.x); b.y=f2bf(v.y); b.z=f2bf(v.z); b.w=f2bf(v.w);
      *(bf4v*)&As[m*40+k4] = b;
    }
    {
      int n = tid>>2, k8 = (tid&3)*8;
      *(bf8s*)&Bs[n*40+k8] = *(const bf8s*)&BT[(size_t)(col0+n)*K + k0 + k8];
    }
    __syncthreads();
    bfv8 af[4], bfr[2];
    #pragma unroll
    for (int mf=0;mf<4;mf++) af[mf] = *(const bfv8*)&As[(wm+mf*16+lm)*40 + lq*8];
    #pragma unroll
    for (int nf=0;nf<2;nf++) bfr[nf] = *(const bfv8*)&Bs[(wn+nf*16+lm)*40 + lq*8];
    #pragma unroll
    for (int mf=0;mf<4;mf++)
      #pragma unroll
      for (int nf=0;nf<2;nf++)
        acc[mf][nf] = __builtin_amdgcn_mfma_f32_16x16x32_bf16(af[mf], bfr[nf], acc[mf][nf], 0,0,0);
    __syncthreads();
  }
  #pragma unroll
  for (int mf=0;mf<4;mf++){
    #pragma unroll
    for (int nf=0;nf<2;nf++){
      int gcol = col0 + wn + nf*16 + lm;
      if (gcol < DPROJ){
        float bia = bias[gcol];
        #pragma unroll
        for (int r=0;r<4;r++){
          int grow = row0 + wm + mf*16 + lq*4 + r;
          float v = acc[mf][nf][r] + bia;
          C[(size_t)grow*DPROJ + gcol] = f2bf(v);
          if (gcol >= 2560) side[grow*8 + (gcol-2560)] = v;
        }
      }
    }
  }
}

// ---------------- GEMM_OUT (MFMA): out(2048x512 fp32) = y2(interleaved ypr bf16) @ W_out --------
__global__ void __launch_bounds__(256) gemmo_mfma(const bf16* __restrict__ Yp, const bf16* __restrict__ BT,
                                                  float* __restrict__ C)
{
  const int K = 1024;
  __shared__ __align__(16) bf16 As[64*40];
  __shared__ __align__(16) bf16 Bs[64*40];
  int tid = threadIdx.x;
  int col0 = blockIdx.x*64, row0 = blockIdx.y*64;
  int wid = tid>>6, lane = tid&63;
  int wm = (wid&1)*32, wn = (wid>>1)*32;
  int lm = lane&15, lq = lane>>4;
  fv4 acc[2][2] = {};
  for (int k0=0;k0<K;k0+=32){
    {
      int m = tid>>2, k8 = (tid&3)*8;
      int kg = k0 + k8;
      *(bf8s*)&As[m*40+k8] = *(const bf8s*)&Yp[(size_t)(row0+m)*2048 + ((kg>>6)*128) + 64 + (kg&63)];
    }
    {
      int n = tid>>2, k8 = (tid&3)*8;
      *(bf8s*)&Bs[n*40+k8] = *(const bf8s*)&BT[(size_t)(col0+n)*K + k0 + k8];
    }
    __syncthreads();
    bfv8 af[2], bfr[2];
    #pragma unroll
    for (int mf=0;mf<2;mf++) af[mf] = *(const bfv8*)&As[(wm+mf*16+lm)*40 + lq*8];
    #pragma unroll
    for (int nf=0;nf<2;nf++) bfr[nf] = *(const bfv8*)&Bs[(wn+nf*16+lm)*40 + lq*8];
    #pragma unroll
    for (int mf=0;mf<2;mf++)
      #pragma unroll
      for (int nf=0;nf<2;nf++)
        acc[mf][nf] = __builtin_amdgcn_mfma_f32_16x16x32_bf16(af[mf], bfr[nf], acc[mf][nf], 0,0,0);
    __syncthreads();
  }
  #pragma unroll
  for (int mf=0;mf<2;mf++)
    #pragma unroll
    for (int nf=0;nf<2;nf++){
      int gcol = col0 + wn + nf*16 + lm;
      #pragma unroll
      for (int r=0;r<4;r++){
        int grow = row0 + wm + mf*16 + lq*4 + r;
        C[(size_t)grow*512 + gcol] = acc[mf][nf][r];
      }
    }
}

// ---------------- K23: dt = softplus, lam = sigmoid, csdt = cumsum_l(dt) (single block) ---------
__global__ void k23(const float* __restrict__ dlraw, float* __restrict__ dtb,
                    float* __restrict__ lamb, float* __restrict__ csdt)
{
  __shared__ float dts[L_SEQ*4];
  __shared__ float segs[4][64];
  int tid = threadIdx.x;
  int g = tid & 3, seg = tid >> 2;
  for (int i = 0; i < 32; i++){
    int l = seg*32 + i;
    float dr = dlraw[l*8 + g];
    float lr = dlraw[l*8 + 4 + g];
    float dt = (dr > 15.f) ? dr : log1pf(__expf(dr));
    dts[l*4+g] = dt;
    dtb[l*4+g] = dt;
    lamb[l*4+g] = 1.f/(1.f+__expf(-lr));
  }
  __syncthreads();
  float s = 0.f;
  for (int i=0;i<32;i++) s += dts[(seg*32+i)*4 + g];
  segs[g][seg] = s;
  __syncthreads();
  if (tid < 4) { float run = 0.f; for (int q=0;q<64;q++){ float t = segs[tid][q]; segs[tid][q] = run; run += t; } }
  __syncthreads();
  float run = segs[g][seg];
  for (int i=0;i<32;i++){ int l = seg*32+i; run += dts[l*4+g]; csdt[l*4+g] = run; }
}

// ---------------- K4: rmsnorm + bias + RoPE -> Br, Cr (bf16, layout [l][g][n*2+r]) --------------
__global__ void k4_rmsrope(const bf16* __restrict__ proj, const float* __restrict__ wB, const float* __restrict__ wC,
                           const float* __restrict__ biasB, const float* __restrict__ biasC,
                           const float* __restrict__ theta_log, const float* __restrict__ csdt,
                           bf16* __restrict__ Br, bf16* __restrict__ Cr)
{
  int l = blockIdx.x;
  int tid = threadIdx.x;
  int g = tid >> 6, idx = tid & 63;
  const bf16* pr = proj + (size_t)l*DPROJ;
  float bv = bf2f(pr[2048 + g*64 + idx]);
  float cv = bf2f(pr[2304 + g*64 + idx]);
  float sb = bv*bv, sc = cv*cv;
  #pragma unroll
  for (int off=32; off; off>>=1){ sb += __shfl_xor(sb, off); sc += __shfl_xor(sc, off); }
  float rb = rsqrtf(sb*(1.f/64.f) + 1e-5f);
  float rc = rsqrtf(sc*(1.f/64.f) + 1e-5f);
  float bm = bv*rb*wB[idx] + biasB[g*64+idx];
  float cm = cv*rc*wC[idx] + biasC[g*64+idx];
  int k = idx >> 2;
  float ang = csdt[l*4+g] * __expf(theta_log[g*16+k]);
  float ca = cosf(ang), sa = sinf(ang);
  float bp = __shfl_xor(bm, 2);
  float cp = __shfl_xor(cm, 2);
  bool is_im = (idx >> 1) & 1;
  float bo = is_im ? (bp*sa + bm*ca) : (bm*ca - bp*sa);
  float co = is_im ? (cp*sa + cm*ca) : (cm*ca - cp*sa);
  Br[((size_t)l*4+g)*64 + idx] = f2bf(bo);
  Cr[((size_t)l*4+g)*64 + idx] = f2bf(co);
}

// ---------------- K5: x_up[l][h][p*2+r] = silu(x) @ W_xup ----------------
__global__ void k5_xup(const bf16* __restrict__ proj, const float* __restrict__ Wx, bf16* __restrict__ xup)
{
  __shared__ __align__(16) float wsm[64*128];
  __shared__ float xs[1024];
  int l = blockIdx.x, tid = threadIdx.x;
  for (int e=tid;e<8192;e+=256) wsm[e] = Wx[e];
  for (int e=tid;e<1024;e+=256){ float v = bf2f(proj[(size_t)l*DPROJ+1024+e]); xs[e] = v/(1.f+__expf(-v)); }
  __syncthreads();
  int h = tid>>4, prb = (tid&15)*8;
  float acc[8] = {};
  for (int k=0;k<64;k++){
    float xv = xs[h*64+k];
    const float4* w4 = (const float4*)&wsm[k*128 + prb];
    float4 a = w4[0], b = w4[1];
    acc[0]+=xv*a.x; acc[1]+=xv*a.y; acc[2]+=xv*a.z; acc[3]+=xv*a.w;
    acc[4]+=xv*b.x; acc[5]+=xv*b.y; acc[6]+=xv*b.z; acc[7]+=xv*b.w;
  }
  bf16* o = xup + ((size_t)l*16+h)*128 + prb;
  stb4(o,   make_float4(acc[0],acc[1],acc[2],acc[3]));
  stb4(o+4, make_float4(acc[4],acc[5],acc[6],acc[7]));
}

// ---------------- K6Y (MFMA): y_diag per (chunk, group, t-quarter) ----------------
__global__ void __launch_bounds__(256) k6y(
  const bf16* __restrict__ Br, const bf16* __restrict__ Cr, const bf16* __restrict__ xup,
  const float* __restrict__ dtb, const float* __restrict__ lamb, const float* __restrict__ A_log,
  bf16* __restrict__ ypr)
{
  __shared__ __align__(16) bf16 Cs[64*40];   // C'[(tl,r1)][n]
  __shared__ __align__(16) bf16 Bs[64*40];   // B'chunk[(r2*32+jjloc)][n]
  __shared__ __align__(16) bf16 Fs[64*72];   // F[(tl,r1)][r2*32+jjloc]
  __shared__ __align__(16) bf16 Xs[64*72];   // X[p][r2*32+jjloc]
  __shared__ float dt_l[128], lam_l[128], cs_l[128];
  int bx = blockIdx.x; int g = bx & 3, q = bx >> 2;
  int c = blockIdx.y;
  int tid = threadIdx.x;
  int l0 = c*TCH;
  int w = tid>>6, lane = tid&63, lm = lane&15, lq = lane>>4;
  float Ah = -__expf(A_log[g]);
  float dt_prev = (c>0) ? dtb[(l0-1)*4+g] : 0.f;
  if (tid<128){ dt_l[tid] = dtb[(l0+tid)*4+g]; lam_l[tid] = lamb[(l0+tid)*4+g]; }
  __syncthreads();
  if (tid<128) cs_l[tid] = dt_l[tid]*Ah;
  __syncthreads();
  for (int off=1; off<128; off<<=1){
    float add = 0.f;
    if (tid<128 && tid>=off) add = cs_l[tid-off];
    __syncthreads();
    if (tid<128) cs_l[tid] += add;
    __syncthreads();
  }
  // stage C' (quarter rows, deinterleave r1)
  for (int e4 = tid; e4 < 512; e4 += 256){
    int tl = e4>>4, c4 = (e4&15)*4;
    bf4v v = *(const bf4v*)&Cr[((size_t)(l0+q*32+tl)*4+g)*64 + c4];
    bf16 arr[4] = {v.x,v.y,v.z,v.w};
    #pragma unroll
    for (int i=0;i<4;i++){ int q6=c4+i; Cs[((tl<<1)|(q6&1))*40 + (q6>>1)] = arr[i]; }
  }
  fv4 acc[4][4] = {};
  int nch = (q+2 < 5) ? (q+2) : 5;
  for (int chunk=0; chunk<nch; chunk++){
    __syncthreads();
    // stage B' chunk (deinterleave r2)
    for (int e4 = tid; e4 < 512; e4 += 256){
      int jjloc = e4>>4, c4 = (e4&15)*4;
      int jj = chunk*32 + jjloc; int l = l0-1+jj;
      bf4v v;
      if (l >= 0 && jj <= 128) v = *(const bf4v*)&Br[((size_t)l*4+g)*64 + c4];
      else { v.x=v.y=v.z=v.w = f2bf(0.f); }
      bf16 arr[4] = {v.x,v.y,v.z,v.w};
      #pragma unroll
      for (int i=0;i<4;i++){ int q6=c4+i; Bs[((q6&1)*32+jjloc)*40 + (q6>>1)] = arr[i]; }
    }
    __syncthreads();
    // GEMM-A: S = C' @ B'^T, scale by coef, write F
    {
      bfv8 a = *(const bfv8*)&Cs[(w*16+lm)*40 + lq*8];
      fv4 zz = {0.f,0.f,0.f,0.f};
      #pragma unroll
      for (int nt=0;nt<4;nt++){
        bfv8 b = *(const bfv8*)&Bs[(nt*16+lm)*40 + lq*8];
        fv4 s = __builtin_amdgcn_mfma_f32_16x16x32_bf16(a, b, zz, 0,0,0);
        int col = nt*16+lm;
        int jj = chunk*32 + (col&31);
        #pragma unroll
        for (int r=0;r<4;r++){
          int row = w*16 + lq*4 + r;
          int T = q*32 + (row>>1);
          float coef = 0.f; float cst = cs_l[T];
          if (jj>=1 && jj<=T+1) coef += lam_l[jj-1]*dt_l[jj-1]*__expf(cst-cs_l[jj-1]);
          if (jj<=T){ float dtx = (jj>=1)? dt_l[jj-1] : dt_prev; coef += (1.f-lam_l[jj])*dtx*__expf(cst-cs_l[jj]); }
          Fs[row*72+col] = f2bf(coef*s[r]);
        }
      }
    }
    __syncthreads();
    for (int h4=0; h4<4; h4++){
      // stage X chunk for head h (transpose + deinterleave r2)
      for (int e4 = tid; e4 < 1024; e4 += 256){
        int jjloc = e4>>5, c4 = (e4&31)*4;
        int jj = chunk*32+jjloc; int l = l0-1+jj;
        bf4v v;
        if (l>=0 && jj<=128) v = *(const bf4v*)&xup[((size_t)l*16 + g*4+h4)*128 + c4];
        else { v.x=v.y=v.z=v.w = f2bf(0.f); }
        bf16 arr[4] = {v.x,v.y,v.z,v.w};
        #pragma unroll
        for (int i=0;i<4;i++){ int q7=c4+i; Xs[(q7>>1)*72 + (q7&1)*32 + jjloc] = arr[i]; }
      }
      __syncthreads();
      #pragma unroll
      for (int r2=0;r2<2;r2++){
        bfv8 a = *(const bfv8*)&Fs[(w*16+lm)*72 + r2*32 + lq*8];
        #pragma unroll
        for (int nt=0;nt<4;nt++){
          bfv8 b = *(const bfv8*)&Xs[(nt*16+lm)*72 + r2*32 + lq*8];
          acc[h4][nt] = __builtin_amdgcn_mfma_f32_16x16x32_bf16(a, b, acc[h4][nt], 0,0,0);
        }
      }
      __syncthreads();
    }
  }
  #pragma unroll
  for (int h4=0;h4<4;h4++)
    #pragma unroll
    for (int nt=0;nt<4;nt++){
      int p = nt*16+lm;
      #pragma unroll
      for (int r=0;r<4;r++){
        int row = w*16+lq*4+r;
        int T = q*32+(row>>1), r1 = row&1;
        ypr[((size_t)(l0+T)*16 + g*4+h4)*128 + p*2+r1] = f2bf(acc[h4][nt][r]);
      }
    }
}

// ---------------- K6H: per (chunk,head): h_final (VALU) + dcb/csb ----------------
__global__ void __launch_bounds__(256) k6h(
  const bf16* __restrict__ Br, const bf16* __restrict__ xup,
  const float* __restrict__ dtb, const float* __restrict__ lamb, const float* __restrict__ A_log,
  bf16* __restrict__ hfin, float* __restrict__ dcb, float* __restrict__ csb)
{
  __shared__ __align__(16) bf16 Bsh[129*68];
  __shared__ __align__(16) bf16 xsh[129*128];
  __shared__ float dt_l[128], lam_l[128], cs_l[128], gco[129];
  int h = blockIdx.x, c = blockIdx.y;
  int g = h >> 2;
  int tid = threadIdx.x;
  int l0 = c * TCH;
  float Ah = -__expf(A_log[g]);
  float dt_prev = (c > 0) ? dtb[(l0-1)*4 + g] : 0.f;
  for (int e = tid; e < 129*16; e += 256) {
    int jj = e >> 4, c4 = (e & 15)*4;
    int l = l0 - 1 + jj;
    if (l >= 0) *(bf4v*)&Bsh[jj*68 + c4] = *(const bf4v*)&Br[((size_t)l*4+g)*64 + c4];
    else { bf4v z; z.x=z.y=z.z=z.w=f2bf(0.f); *(bf4v*)&Bsh[jj*68 + c4] = z; }
  }
  for (int e = tid; e < 129*32; e += 256) {
    int jj = e >> 5, c4 = (e & 31)*4;
    int l = l0 - 1 + jj;
    if (l >= 0) *(bf4v*)&xsh[jj*128 + c4] = *(const bf4v*)&xup[((size_t)l*16+h)*128 + c4];
    else { bf4v z; z.x=z.y=z.z=z.w=f2bf(0.f); *(bf4v*)&xsh[jj*128 + c4] = z; }
  }
  if (tid < 128) {
    dt_l[tid]  = dtb[(l0+tid)*4+g];
    lam_l[tid] = lamb[(l0+tid)*4+g];
  }
  __syncthreads();
  if (tid < 128) cs_l[tid] = dt_l[tid] * Ah;
  __syncthreads();
  for (int off = 1; off < 128; off <<= 1) {
    float add = 0.f;
    if (tid < 128 && tid >= off) add = cs_l[tid - off];
    __syncthreads();
    if (tid < 128) cs_l[tid] += add;
    __syncthreads();
  }
  if (tid == 0) dcb[c*16+h] = __expf(cs_l[127]);
  if ((h & 3) == 0 && tid < 128) csb[(c*4+g)*128 + tid] = cs_l[tid];
  __syncthreads();
  if (tid < 129) {
    int jj = tid;
    float gc = 0.f;
    float cst = cs_l[127];
    if (jj >= 1) gc += lam_l[jj-1]*dt_l[jj-1]*__expf(cst - cs_l[jj-1]);
    if (jj <= 127) {
      float dtx = (jj >= 1) ? dt_l[jj-1] : dt_prev;
      gc += (1.f - lam_l[jj]) * dtx * __expf(cst - cs_l[jj]);
    }
    gco[jj] = gc;
  }
  __syncthreads();
  int jjstart = (c == 0) ? 1 : 0;
  {
    int n = tid >> 3, pg = tid & 7;
    float acc[8] = {};
    for (int jj = jjstart; jj <= 128; jj++) {
      float gcv = gco[jj];
      unsigned bb = *(const unsigned*)&Bsh[jj*68 + n*2];
      float bx = gcv*blo(bb), by = gcv*bhi(bb);
      const uint2* xr = (const uint2*)&xsh[jj*128 + 16*pg];
      #pragma unroll
      for (int i=0;i<4;i++){
        uint2 xu = xr[i];
        float x0 = blo(xu.x), x1 = bhi(xu.x), x2 = blo(xu.y), x3 = bhi(xu.y);
        acc[2*i]   += bx*x0 + by*x1;
        acc[2*i+1] += bx*x2 + by*x3;
      }
    }
    bf16* hp = hfin + (((size_t)c*16+h)*32 + n)*64 + pg*8;
    stb4(hp,   make_float4(acc[0],acc[1],acc[2],acc[3]));
    stb4(hp+4, make_float4(acc[4],acc[5],acc[6],acc[7]));
  }
}

// ---------------- K7: inter-chunk scan ----------------
__global__ void k7_scan(const bf16* __restrict__ hfin, const float* __restrict__ dcb, bf16* __restrict__ hstb)
{
  int h = blockIdx.x, tid = threadIdx.x;
  float carry[8] = {};
  for (int c = 0; c < NCHUNK; c++) {
    float dc = dcb[c*16+h];
    size_t base = ((size_t)c*16+h)*2048;
    #pragma unroll
    for (int i=0;i<8;i++){
      int e = tid + i*256;
      hstb[base+e] = f2bf(carry[i]);
      carry[i] = carry[i]*dc + bf2f(hfin[base+e]);
    }
  }
}

// ---------------- K8A (MFMA): ypr += cse[t] * (C' @ h^T) ----------------
__global__ void __launch_bounds__(256) k8a_mfma(const bf16* __restrict__ Cr, const bf16* __restrict__ hstb,
                                                const float* __restrict__ csb, bf16* __restrict__ ypr)
{
  __shared__ __align__(16) bf16 C2s[256*40];  // [(tl,r1)][n]
  __shared__ __align__(16) bf16 hT[64*40];    // [p][n]
  __shared__ float cse[128];
  int h = blockIdx.x, c = blockIdx.y;
  int g = h >> 2;
  int tid = threadIdx.x;
  int l0 = c*TCH;
  int w = tid>>6, lane = tid&63, lm = lane&15, lq = lane>>4;
  for (int e4 = tid; e4 < 2048; e4 += 256){
    int tl = e4>>4, c4 = (e4&15)*4;
    bf4v v = *(const bf4v*)&Cr[((size_t)(l0+tl)*4+g)*64 + c4];
    bf16 arr[4] = {v.x,v.y,v.z,v.w};
    #pragma unroll
    for (int i=0;i<4;i++){ int q6=c4+i; C2s[((tl<<1)|(q6&1))*40 + (q6>>1)] = arr[i]; }
  }
  for (int e4 = tid; e4 < 512; e4 += 256){
    int n = e4>>4, p4 = (e4&15)*4;
    bf4v v = *(const bf4v*)&hstb[((size_t)c*16+h)*2048 + n*64 + p4];
    bf16 arr[4] = {v.x,v.y,v.z,v.w};
    #pragma unroll
    for (int i=0;i<4;i++) hT[(p4+i)*40 + n] = arr[i];
  }
  if (tid < 128) cse[tid] = __expf(csb[(c*4+g)*128 + tid]);
  __syncthreads();
  fv4 zz = {0.f,0.f,0.f,0.f};
  #pragma unroll
  for (int mi=0;mi<4;mi++){
    int mt = w*4 + mi;
    bfv8 a = *(const bfv8*)&C2s[(mt*16+lm)*40 + lq*8];
    #pragma unroll
    for (int nt=0;nt<4;nt++){
      bfv8 b = *(const bfv8*)&hT[(nt*16+lm)*40 + lq*8];
      fv4 s = __builtin_amdgcn_mfma_f32_16x16x32_bf16(a, b, zz, 0,0,0);
      int p = nt*16+lm;
      #pragma unroll
      for (int r=0;r<4;r++){
        int row = mt*16+lq*4+r;
        int tl = row>>1, r1 = row&1;
        size_t idx = ((size_t)(l0+tl)*16 + h)*128 + p*2 + r1;
        ypr[idx] = f2bf(bf2f(ypr[idx]) + cse[tl]*s[r]);
      }
    }
  }
}

// ---- K8B: ydown + D*silu(x), * silu(z); writes y2 into upper-half slots of ypr rows ----
__global__ void k8b_ydown(bf16* __restrict__ ypr, const float* __restrict__ Wyd,
                          const bf16* __restrict__ proj, const float* __restrict__ Dp)
{
  __shared__ __align__(16) float wsh[128*64];
  __shared__ float ysh[2048];
  int l = blockIdx.x, tid = threadIdx.x;
  for (int e=tid;e<8192;e+=256) wsh[e] = Wyd[e];
  for (int e=tid;e<2048;e+=256) ysh[e] = bf2f(ypr[(size_t)l*2048 + e]);
  __syncthreads();
  int h = tid >> 4, q0 = (tid & 15) * 4;
  float acc[4] = {};
  for (int k=0;k<128;k++){
    float yv = ysh[h*128 + k];
    float4 wv = *(const float4*)&wsh[k*64 + q0];
    acc[0]+=yv*wv.x; acc[1]+=yv*wv.y; acc[2]+=yv*wv.z; acc[3]+=yv*wv.w;
  }
  float dv = Dp[h];
  const bf16* pr = proj + (size_t)l*DPROJ;
  float4 xq = ldb4(pr + 1024 + h*64 + q0);
  float4 zq = ldb4(pr + h*64 + q0);
  float xv[4] = {xq.x,xq.y,xq.z,xq.w};
  float zv[4] = {zq.x,zq.y,zq.z,zq.w};
  float outv[4];
  #pragma unroll
  for (int i=0;i<4;i++){
    float xs = xv[i]/(1.f+__expf(-xv[i]));
    float zs = zv[i]/(1.f+__expf(-zv[i]));
    outv[i] = (acc[i] + dv*xs) * zs;
  }
  stb4(ypr + (size_t)l*2048 + h*128 + 64 + q0, make_float4(outv[0],outv[1],outv[2],outv[3]));
}

extern "C" void kernel_launch(void* const* d_in, const int* in_sizes, int n_in,
                              void* d_out, int out_size, void* d_ws, size_t ws_size,
                              hipStream_t stream) {
  const float* u       = (const float*)d_in[0];
  const float* W_in    = (const float*)d_in[1];
  const float* b_in    = (const float*)d_in[2];
  const float* W_xup   = (const float*)d_in[3];
  const float* W_ydown = (const float*)d_in[4];
  const float* A_log   = (const float*)d_in[5];
  const float* theta_l = (const float*)d_in[6];
  const float* D_p     = (const float*)d_in[7];
  const float* wB      = (const float*)d_in[8];
  const float* wC      = (const float*)d_in[9];
  const float* biasB   = (const float*)d_in[10];
  const float* biasC   = (const float*)d_in[11];
  const float* W_out   = (const float*)d_in[12];
  float* out = (float*)d_out;

  char* w = (char*)d_ws;
  bf16*  proj  = (bf16*)(w);                       // 10,518,528 B
  float* dlraw = (float*)(w + 10518528);           //     65,536 B
  float* dtb   = (float*)(w + 10584064);           //     32,768 B
  float* lamb  = (float*)(w + 10616832);           //     32,768 B
  float* csdt  = (float*)(w + 10649600);           //     32,768 B
  bf16*  Brb   = (bf16*)(w + 10682368);            //  1,048,576 B
  bf16*  Crb   = (bf16*)(w + 11730944);            //  1,048,576 B
  bf16*  xupb  = (bf16*)(w + 12779520);            //  8,388,608 B
  bf16*  hfin  = (bf16*)(w + 21168128);            //  1,048,576 B
  bf16*  hstb  = (bf16*)(w + 22216704);            //  1,048,576 B
  float* dcb   = (float*)(w + 23265280);           //      1,024 B
  float* csb   = (float*)(w + 23266304);           //     32,768 B
  bf16*  ypr   = (bf16*)(w + 23299072);            //  8,388,608 B
  bf16*  WinT  = (bf16*)(w + 23299072);            //  aliased (dead once k6y writes ypr)
  bf16*  WoutT = (bf16*)(w + 10682368);            //  aliased over Brb (dead after k8a)

  tcastT<<<dim3(82,16),256,0,stream>>>(W_in, WinT, 512, DPROJ, 2624);
  gemm1_mfma<<<dim3(41,16),256,0,stream>>>(u, WinT, b_in, proj, dlraw);
  k23<<<1,256,0,stream>>>(dlraw, dtb, lamb, csdt);
  k4_rmsrope<<<2048,256,0,stream>>>(proj, wB, wC, biasB, biasC, theta_l, csdt, Brb, Crb);
  k5_xup<<<2048,256,0,stream>>>(proj, W_xup, xupb);
  k6h<<<dim3(16,16),256,0,stream>>>(Brb, xupb, dtb, lamb, A_log, hfin, dcb, csb);
  k6y<<<dim3(16,16),256,0,stream>>>(Brb, Crb, xupb, dtb, lamb, A_log, ypr);
  k7_scan<<<16,256,0,stream>>>(hfin, dcb, hstb);
  k8a_mfma<<<dim3(16,16),256,0,stream>>>(Crb, hstb, csb, ypr);
  tcastT<<<dim3(16,32),256,0,stream>>>(W_out, WoutT, 1024, 512, 512);
  k8b_ydown<<<2048,256,0,stream>>>(ypr, W_ydown, proj, D_p);
  gemmo_mfma<<<dim3(8,32),256,0,stream>>>(ypr, WoutT, out);
}

// Round 6
// 253.313 us; speedup vs baseline: 2.1862x; 1.0997x over previous
//
#include <hip/hip_runtime.h>
#include <hip/hip_bf16.h>

typedef __hip_bfloat16 bf16;
typedef __bf16 bfv8 __attribute__((ext_vector_type(8)));
typedef float fv4 __attribute__((ext_vector_type(4)));

__device__ __forceinline__ float bf2f(bf16 x){ return __bfloat162float(x); }
__device__ __forceinline__ bf16 f2bf(float x){ return __float2bfloat16(x); }
__device__ __forceinline__ float blo(unsigned u){ return __uint_as_float(u<<16); }
__device__ __forceinline__ float bhi(unsigned u){ return __uint_as_float(u & 0xffff0000u); }
struct __align__(8) bf4v { bf16 x,y,z,w; };
struct __align__(16) bf8s { ushort u[8]; };
__device__ __forceinline__ float4 ldb4(const bf16* p){
  ushort4 u = *(const ushort4*)p;
  float4 r;
  r.x = __uint_as_float(((unsigned)u.x)<<16);
  r.y = __uint_as_float(((unsigned)u.y)<<16);
  r.z = __uint_as_float(((unsigned)u.z)<<16);
  r.w = __uint_as_float(((unsigned)u.w)<<16);
  return r;
}
__device__ __forceinline__ void stb4(bf16* p, float4 v){
  bf4v t; t.x=f2bf(v.x); t.y=f2bf(v.y); t.z=f2bf(v.z); t.w=f2bf(v.w);
  *(bf4v*)p = t;
}

#define L_SEQ 2048
#define DPROJ 2568
#define NCHUNK 16
#define TCH 128

// ---------------- tcastT: out[C][R] (bf16, rows padded to Cpad with zeros) = in[R][C]^T ---------
__global__ void tcastT(const float* __restrict__ in, bf16* __restrict__ out, int R, int C, int Cpad)
{
  __shared__ float t[32][33];
  int c0 = blockIdx.x*32, r0 = blockIdx.y*32;
  int tx = threadIdx.x & 31, ty = threadIdx.x >> 5;
  for (int i=0;i<32;i+=8){
    int r = r0+i+ty, cc = c0+tx;
    t[i+ty][tx] = (r<R && cc<C) ? in[(size_t)r*C+cc] : 0.f;
  }
  __syncthreads();
  for (int i=0;i<32;i+=8){
    int cc = c0+i+ty, r = r0+tx;
    if (cc<Cpad && r<R) out[(size_t)cc*R + r] = f2bf(t[tx][i+ty]);
  }
}

// ---------------- GEMM1 (MFMA): proj(2048x2568 bf16) = u(fp32) @ W_in + b_in; side fp32 --------
__global__ void __launch_bounds__(256) gemm1_mfma(const float* __restrict__ A, const bf16* __restrict__ BT,
                                                  const float* __restrict__ bias, bf16* __restrict__ C,
                                                  float* __restrict__ side)
{
  const int K = 512;
  __shared__ __align__(16) bf16 As[128*40];
  __shared__ __align__(16) bf16 Bs[64*40];
  int tid = threadIdx.x;
  int col0 = blockIdx.x*64, row0 = blockIdx.y*128;
  int wid = tid>>6, lane = tid&63;
  int wm = (wid&1)*64, wn = (wid>>1)*32;
  int lm = lane&15, lq = lane>>4;
  fv4 acc[4][2] = {};
  for (int k0=0;k0<K;k0+=32){
    #pragma unroll
    for (int i=0;i<4;i++){
      int m = i*32 + (tid>>3);
      int k4 = (tid&7)*4;
      float4 v = *(const float4*)&A[(size_t)(row0+m)*K + k0 + k4];
      bf4v b; b.x=f2bf(v.x); b.y=f2bf(v.y); b.z=f2bf(v.z); b.w=f2bf(v.w);
      *(bf4v*)&As[m*40+k4] = b;
    }
    {
      int n = tid>>2, k8 = (tid&3)*8;
      *(bf8s*)&Bs[n*40+k8] = *(const bf8s*)&BT[(size_t)(col0+n)*K + k0 + k8];
    }
    __syncthreads();
    bfv8 af[4], bfr[2];
    #pragma unroll
    for (int mf=0;mf<4;mf++) af[mf] = *(const bfv8*)&As[(wm+mf*16+lm)*40 + lq*8];
    #pragma unroll
    for (int nf=0;nf<2;nf++) bfr[nf] = *(const bfv8*)&Bs[(wn+nf*16+lm)*40 + lq*8];
    #pragma unroll
    for (int mf=0;mf<4;mf++)
      #pragma unroll
      for (int nf=0;nf<2;nf++)
        acc[mf][nf] = __builtin_amdgcn_mfma_f32_16x16x32_bf16(af[mf], bfr[nf], acc[mf][nf], 0,0,0);
    __syncthreads();
  }
  #pragma unroll
  for (int mf=0;mf<4;mf++){
    #pragma unroll
    for (int nf=0;nf<2;nf++){
      int gcol = col0 + wn + nf*16 + lm;
      if (gcol < DPROJ){
        float bia = bias[gcol];
        #pragma unroll
        for (int r=0;r<4;r++){
          int grow = row0 + wm + mf*16 + lq*4 + r;
          float v = acc[mf][nf][r] + bia;
          C[(size_t)grow*DPROJ + gcol] = f2bf(v);
          if (gcol >= 2560) side[grow*8 + (gcol-2560)] = v;
        }
      }
    }
  }
}

// ---------------- GEMM_OUT (MFMA): out(2048x512 fp32) = y2(interleaved ypr bf16) @ W_out --------
__global__ void __launch_bounds__(256) gemmo_mfma(const bf16* __restrict__ Yp, const bf16* __restrict__ BT,
                                                  float* __restrict__ C)
{
  const int K = 1024;
  __shared__ __align__(16) bf16 As[64*40];
  __shared__ __align__(16) bf16 Bs[64*40];
  int tid = threadIdx.x;
  int col0 = blockIdx.x*64, row0 = blockIdx.y*64;
  int wid = tid>>6, lane = tid&63;
  int wm = (wid&1)*32, wn = (wid>>1)*32;
  int lm = lane&15, lq = lane>>4;
  fv4 acc[2][2] = {};
  for (int k0=0;k0<K;k0+=32){
    {
      int m = tid>>2, k8 = (tid&3)*8;
      int kg = k0 + k8;
      *(bf8s*)&As[m*40+k8] = *(const bf8s*)&Yp[(size_t)(row0+m)*2048 + ((kg>>6)*128) + 64 + (kg&63)];
    }
    {
      int n = tid>>2, k8 = (tid&3)*8;
      *(bf8s*)&Bs[n*40+k8] = *(const bf8s*)&BT[(size_t)(col0+n)*K + k0 + k8];
    }
    __syncthreads();
    bfv8 af[2], bfr[2];
    #pragma unroll
    for (int mf=0;mf<2;mf++) af[mf] = *(const bfv8*)&As[(wm+mf*16+lm)*40 + lq*8];
    #pragma unroll
    for (int nf=0;nf<2;nf++) bfr[nf] = *(const bfv8*)&Bs[(wn+nf*16+lm)*40 + lq*8];
    #pragma unroll
    for (int mf=0;mf<2;mf++)
      #pragma unroll
      for (int nf=0;nf<2;nf++)
        acc[mf][nf] = __builtin_amdgcn_mfma_f32_16x16x32_bf16(af[mf], bfr[nf], acc[mf][nf], 0,0,0);
    __syncthreads();
  }
  #pragma unroll
  for (int mf=0;mf<2;mf++)
    #pragma unroll
    for (int nf=0;nf<2;nf++){
      int gcol = col0 + wn + nf*16 + lm;
      #pragma unroll
      for (int r=0;r<4;r++){
        int grow = row0 + wm + mf*16 + lq*4 + r;
        C[(size_t)grow*512 + gcol] = acc[mf][nf][r];
      }
    }
}

// ---------------- K23: dt = softplus, lam = sigmoid, csdt = cumsum_l(dt) (single block) ---------
__global__ void k23(const float* __restrict__ dlraw, float* __restrict__ dtb,
                    float* __restrict__ lamb, float* __restrict__ csdt)
{
  __shared__ float dts[L_SEQ*4];
  __shared__ float segs[4][64];
  int tid = threadIdx.x;
  int g = tid & 3, seg = tid >> 2;
  for (int i = 0; i < 32; i++){
    int l = seg*32 + i;
    float dr = dlraw[l*8 + g];
    float lr = dlraw[l*8 + 4 + g];
    float dt = (dr > 15.f) ? dr : log1pf(__expf(dr));
    dts[l*4+g] = dt;
    dtb[l*4+g] = dt;
    lamb[l*4+g] = 1.f/(1.f+__expf(-lr));
  }
  __syncthreads();
  float s = 0.f;
  for (int i=0;i<32;i++) s += dts[(seg*32+i)*4 + g];
  segs[g][seg] = s;
  __syncthreads();
  if (tid < 4) { float run = 0.f; for (int q=0;q<64;q++){ float t = segs[tid][q]; segs[tid][q] = run; run += t; } }
  __syncthreads();
  float run = segs[g][seg];
  for (int i=0;i<32;i++){ int l = seg*32+i; run += dts[l*4+g]; csdt[l*4+g] = run; }
}

// ---------------- K4: rmsnorm + bias + RoPE -> Br, Cr (bf16, layout [l][g][n*2+r]) --------------
__global__ void k4_rmsrope(const bf16* __restrict__ proj, const float* __restrict__ wB, const float* __restrict__ wC,
                           const float* __restrict__ biasB, const float* __restrict__ biasC,
                           const float* __restrict__ theta_log, const float* __restrict__ csdt,
                           bf16* __restrict__ Br, bf16* __restrict__ Cr)
{
  int l = blockIdx.x;
  int tid = threadIdx.x;
  int g = tid >> 6, idx = tid & 63;
  const bf16* pr = proj + (size_t)l*DPROJ;
  float bv = bf2f(pr[2048 + g*64 + idx]);
  float cv = bf2f(pr[2304 + g*64 + idx]);
  float sb = bv*bv, sc = cv*cv;
  #pragma unroll
  for (int off=32; off; off>>=1){ sb += __shfl_xor(sb, off); sc += __shfl_xor(sc, off); }
  float rb = rsqrtf(sb*(1.f/64.f) + 1e-5f);
  float rc = rsqrtf(sc*(1.f/64.f) + 1e-5f);
  float bm = bv*rb*wB[idx] + biasB[g*64+idx];
  float cm = cv*rc*wC[idx] + biasC[g*64+idx];
  int k = idx >> 2;
  float ang = csdt[l*4+g] * __expf(theta_log[g*16+k]);
  float ca = cosf(ang), sa = sinf(ang);
  float bp = __shfl_xor(bm, 2);
  float cp = __shfl_xor(cm, 2);
  bool is_im = (idx >> 1) & 1;
  float bo = is_im ? (bp*sa + bm*ca) : (bm*ca - bp*sa);
  float co = is_im ? (cp*sa + cm*ca) : (cm*ca - cp*sa);
  Br[((size_t)l*4+g)*64 + idx] = f2bf(bo);
  Cr[((size_t)l*4+g)*64 + idx] = f2bf(co);
}

// ---------------- K5: x_up[l][h][p*2+r] = silu(x) @ W_xup ----------------
__global__ void k5_xup(const bf16* __restrict__ proj, const float* __restrict__ Wx, bf16* __restrict__ xup)
{
  __shared__ __align__(16) float wsm[64*128];
  __shared__ float xs[1024];
  int l = blockIdx.x, tid = threadIdx.x;
  for (int e=tid;e<8192;e+=256) wsm[e] = Wx[e];
  for (int e=tid;e<1024;e+=256){ float v = bf2f(proj[(size_t)l*DPROJ+1024+e]); xs[e] = v/(1.f+__expf(-v)); }
  __syncthreads();
  int h = tid>>4, prb = (tid&15)*8;
  float acc[8] = {};
  for (int k=0;k<64;k++){
    float xv = xs[h*64+k];
    const float4* w4 = (const float4*)&wsm[k*128 + prb];
    float4 a = w4[0], b = w4[1];
    acc[0]+=xv*a.x; acc[1]+=xv*a.y; acc[2]+=xv*a.z; acc[3]+=xv*a.w;
    acc[4]+=xv*b.x; acc[5]+=xv*b.y; acc[6]+=xv*b.z; acc[7]+=xv*b.w;
  }
  bf16* o = xup + ((size_t)l*16+h)*128 + prb;
  stb4(o,   make_float4(acc[0],acc[1],acc[2],acc[3]));
  stb4(o+4, make_float4(acc[4],acc[5],acc[6],acc[7]));
}

// ---------------- K6Y (MFMA): y_diag per (chunk, group, t-quarter, head) ----------------
__global__ void __launch_bounds__(256) k6y(
  const bf16* __restrict__ Br, const bf16* __restrict__ Cr, const bf16* __restrict__ xup,
  const float* __restrict__ dtb, const float* __restrict__ lamb, const float* __restrict__ A_log,
  bf16* __restrict__ ypr)
{
  __shared__ __align__(16) bf16 Cs[64*40];   // C'[(tl,r1)][n]
  __shared__ __align__(16) bf16 Bs[64*40];   // B'chunk[(r2*32+jjloc)][n]
  __shared__ __align__(16) bf16 Fs[64*72];   // F[(tl,r1)][r2*32+jjloc]
  __shared__ __align__(16) bf16 Xs[64*72];   // X[p][r2*32+jjloc]
  __shared__ float dt_l[128], lam_l[128], cs_l[128];
  int bx = blockIdx.x; int g = bx & 3, q = bx >> 2;
  int c = blockIdx.y;
  int h4 = blockIdx.z;
  int h = g*4 + h4;
  int tid = threadIdx.x;
  int l0 = c*TCH;
  int w = tid>>6, lane = tid&63, lm = lane&15, lq = lane>>4;
  float Ah = -__expf(A_log[g]);
  float dt_prev = (c>0) ? dtb[(l0-1)*4+g] : 0.f;
  if (tid<128){ dt_l[tid] = dtb[(l0+tid)*4+g]; lam_l[tid] = lamb[(l0+tid)*4+g]; }
  __syncthreads();
  if (tid<128) cs_l[tid] = dt_l[tid]*Ah;
  __syncthreads();
  for (int off=1; off<128; off<<=1){
    float add = 0.f;
    if (tid<128 && tid>=off) add = cs_l[tid-off];
    __syncthreads();
    if (tid<128) cs_l[tid] += add;
    __syncthreads();
  }
  // stage C' (quarter rows, deinterleave r1)
  for (int e4 = tid; e4 < 512; e4 += 256){
    int tl = e4>>4, c4 = (e4&15)*4;
    bf4v v = *(const bf4v*)&Cr[((size_t)(l0+q*32+tl)*4+g)*64 + c4];
    bf16 arr[4] = {v.x,v.y,v.z,v.w};
    #pragma unroll
    for (int i=0;i<4;i++){ int q6=c4+i; Cs[((tl<<1)|(q6&1))*40 + (q6>>1)] = arr[i]; }
  }
  fv4 acc[4] = {};
  int nch = (q+2 < 5) ? (q+2) : 5;
  for (int kc=0; kc<nch; kc++){
    // stage B' chunk (deinterleave r2)
    for (int e4 = tid; e4 < 512; e4 += 256){
      int jjloc = e4>>4, c4 = (e4&15)*4;
      int jj = kc*32 + jjloc; int l = l0-1+jj;
      bf4v v;
      if (l >= 0 && jj <= 128) v = *(const bf4v*)&Br[((size_t)l*4+g)*64 + c4];
      else { v.x=v.y=v.z=v.w = f2bf(0.f); }
      bf16 arr[4] = {v.x,v.y,v.z,v.w};
      #pragma unroll
      for (int i=0;i<4;i++){ int q6=c4+i; Bs[((q6&1)*32+jjloc)*40 + (q6>>1)] = arr[i]; }
    }
    // stage X chunk for head h (transpose + deinterleave r2)
    for (int e4 = tid; e4 < 1024; e4 += 256){
      int jjloc = e4>>5, c4 = (e4&31)*4;
      int jj = kc*32+jjloc; int l = l0-1+jj;
      bf4v v;
      if (l>=0 && jj<=128) v = *(const bf4v*)&xup[((size_t)l*16 + h)*128 + c4];
      else { v.x=v.y=v.z=v.w = f2bf(0.f); }
      bf16 arr[4] = {v.x,v.y,v.z,v.w};
      #pragma unroll
      for (int i=0;i<4;i++){ int q7=c4+i; Xs[(q7>>1)*72 + (q7&1)*32 + jjloc] = arr[i]; }
    }
    __syncthreads();
    // GEMM-A: S = C' @ B'^T, scale by coef, write F
    {
      bfv8 a = *(const bfv8*)&Cs[(w*16+lm)*40 + lq*8];
      fv4 zz = {0.f,0.f,0.f,0.f};
      #pragma unroll
      for (int nt=0;nt<4;nt++){
        bfv8 b = *(const bfv8*)&Bs[(nt*16+lm)*40 + lq*8];
        fv4 s = __builtin_amdgcn_mfma_f32_16x16x32_bf16(a, b, zz, 0,0,0);
        int col = nt*16+lm;
        int jj = kc*32 + (col&31);
        #pragma unroll
        for (int r=0;r<4;r++){
          int row = w*16 + lq*4 + r;
          int T = q*32 + (row>>1);
          float coef = 0.f; float cst = cs_l[T];
          if (jj>=1 && jj<=T+1) coef += lam_l[jj-1]*dt_l[jj-1]*__expf(cst-cs_l[jj-1]);
          if (jj<=T){ float dtx = (jj>=1)? dt_l[jj-1] : dt_prev; coef += (1.f-lam_l[jj])*dtx*__expf(cst-cs_l[jj]); }
          Fs[row*72+col] = f2bf(coef*s[r]);
        }
      }
    }
    __syncthreads();
    // GEMM-B: acc += F @ X^T
    #pragma unroll
    for (int r2=0;r2<2;r2++){
      bfv8 a = *(const bfv8*)&Fs[(w*16+lm)*72 + r2*32 + lq*8];
      #pragma unroll
      for (int nt=0;nt<4;nt++){
        bfv8 b = *(const bfv8*)&Xs[(nt*16+lm)*72 + r2*32 + lq*8];
        acc[nt] = __builtin_amdgcn_mfma_f32_16x16x32_bf16(a, b, acc[nt], 0,0,0);
      }
    }
    __syncthreads();
  }
  #pragma unroll
  for (int nt=0;nt<4;nt++){
    int p = nt*16+lm;
    #pragma unroll
    for (int r=0;r<4;r++){
      int row = w*16+lq*4+r;
      int T = q*32+(row>>1), r1 = row&1;
      ypr[((size_t)(l0+T)*16 + h)*128 + p*2+r1] = f2bf(acc[nt][r]);
    }
  }
}

// ---------------- K6H: per (chunk,head,zhalf): partial h_final (VALU) + dcb/csb ----------------
__global__ void __launch_bounds__(256) k6h(
  const bf16* __restrict__ Br, const bf16* __restrict__ xup,
  const float* __restrict__ dtb, const float* __restrict__ lamb, const float* __restrict__ A_log,
  bf16* __restrict__ hfp0, bf16* __restrict__ hfp1, float* __restrict__ dcb, float* __restrict__ csb)
{
  __shared__ __align__(16) bf16 Bsh[65*68];
  __shared__ __align__(16) bf16 xsh[65*128];
  __shared__ float dt_l[128], lam_l[128], cs_l[128], gco[65];
  int h = blockIdx.x, c = blockIdx.y, z = blockIdx.z;
  int g = h >> 2;
  int tid = threadIdx.x;
  int l0 = c * TCH;
  int jbase = z*64;
  int nrow = z ? 65 : 64;
  float Ah = -__expf(A_log[g]);
  float dt_prev = (c > 0) ? dtb[(l0-1)*4 + g] : 0.f;
  for (int e = tid; e < nrow*16; e += 256) {
    int jjl = e >> 4, c4 = (e & 15)*4;
    int l = l0 - 1 + jbase + jjl;
    if (l >= 0) *(bf4v*)&Bsh[jjl*68 + c4] = *(const bf4v*)&Br[((size_t)l*4+g)*64 + c4];
    else { bf4v zv; zv.x=zv.y=zv.z=zv.w=f2bf(0.f); *(bf4v*)&Bsh[jjl*68 + c4] = zv; }
  }
  for (int e = tid; e < nrow*32; e += 256) {
    int jjl = e >> 5, c4 = (e & 31)*4;
    int l = l0 - 1 + jbase + jjl;
    if (l >= 0) *(bf4v*)&xsh[jjl*128 + c4] = *(const bf4v*)&xup[((size_t)l*16+h)*128 + c4];
    else { bf4v zv; zv.x=zv.y=zv.z=zv.w=f2bf(0.f); *(bf4v*)&xsh[jjl*128 + c4] = zv; }
  }
  if (tid < 128) {
    dt_l[tid]  = dtb[(l0+tid)*4+g];
    lam_l[tid] = lamb[(l0+tid)*4+g];
  }
  __syncthreads();
  if (tid < 128) cs_l[tid] = dt_l[tid] * Ah;
  __syncthreads();
  for (int off = 1; off < 128; off <<= 1) {
    float add = 0.f;
    if (tid < 128 && tid >= off) add = cs_l[tid - off];
    __syncthreads();
    if (tid < 128) cs_l[tid] += add;
    __syncthreads();
  }
  if (z == 0 && tid == 0) dcb[c*16+h] = __expf(cs_l[127]);
  if (z == 0 && (h & 3) == 0 && tid < 128) csb[(c*4+g)*128 + tid] = cs_l[tid];
  __syncthreads();
  if (tid < nrow) {
    int jj = jbase + tid;
    float gc = 0.f;
    float cst = cs_l[127];
    if (jj >= 1) gc += lam_l[jj-1]*dt_l[jj-1]*__expf(cst - cs_l[jj-1]);
    if (jj <= 127) {
      float dtx = (jj >= 1) ? dt_l[jj-1] : dt_prev;
      gc += (1.f - lam_l[jj]) * dtx * __expf(cst - cs_l[jj]);
    }
    gco[tid] = gc;
  }
  __syncthreads();
  int jstart = (z == 0 && c == 0) ? 1 : 0;
  {
    int n = tid >> 3, pg = tid & 7;
    float acc[8] = {};
    for (int jjl = jstart; jjl < nrow; jjl++) {
      float gcv = gco[jjl];
      unsigned bb = *(const unsigned*)&Bsh[jjl*68 + n*2];
      float bx = gcv*blo(bb), by = gcv*bhi(bb);
      const uint2* xr = (const uint2*)&xsh[jjl*128 + 16*pg];
      #pragma unroll
      for (int i=0;i<4;i++){
        uint2 xu = xr[i];
        float x0 = blo(xu.x), x1 = bhi(xu.x), x2 = blo(xu.y), x3 = bhi(xu.y);
        acc[2*i]   += bx*x0 + by*x1;
        acc[2*i+1] += bx*x2 + by*x3;
      }
    }
    bf16* hp = (z ? hfp1 : hfp0) + (((size_t)c*16+h)*32 + n)*64 + pg*8;
    stb4(hp,   make_float4(acc[0],acc[1],acc[2],acc[3]));
    stb4(hp+4, make_float4(acc[4],acc[5],acc[6],acc[7]));
  }
}

// ---------------- K7: inter-chunk scan (reads two partials; hfp1 may alias hstb) ----------------
__global__ void k7_scan(const bf16* __restrict__ hfp0, const bf16* __restrict__ hfp1,
                        const float* __restrict__ dcb, bf16* __restrict__ hstb)
{
  int h = blockIdx.x, tid = threadIdx.x;
  float carry[8] = {};
  for (int c = 0; c < NCHUNK; c++) {
    float dc = dcb[c*16+h];
    size_t base = ((size_t)c*16+h)*2048;
    #pragma unroll
    for (int i=0;i<8;i++){
      int e = tid + i*256;
      float p = bf2f(hfp0[base+e]) + bf2f(hfp1[base+e]);   // read BEFORE hstb write (aliasing-safe)
      hstb[base+e] = f2bf(carry[i]);
      carry[i] = carry[i]*dc + p;
    }
  }
}

// ---------------- K8A (MFMA): ypr += cse[t] * (C' @ h^T) ----------------
__global__ void __launch_bounds__(256) k8a_mfma(const bf16* __restrict__ Cr, const bf16* __restrict__ hstb,
                                                const float* __restrict__ csb, bf16* __restrict__ ypr)
{
  __shared__ __align__(16) bf16 C2s[256*40];  // [(tl,r1)][n]
  __shared__ __align__(16) bf16 hT[64*40];    // [p][n]
  __shared__ float cse[128];
  int h = blockIdx.x, c = blockIdx.y;
  int g = h >> 2;
  int tid = threadIdx.x;
  int l0 = c*TCH;
  int w = tid>>6, lane = tid&63, lm = lane&15, lq = lane>>4;
  for (int e4 = tid; e4 < 2048; e4 += 256){
    int tl = e4>>4, c4 = (e4&15)*4;
    bf4v v = *(const bf4v*)&Cr[((size_t)(l0+tl)*4+g)*64 + c4];
    bf16 arr[4] = {v.x,v.y,v.z,v.w};
    #pragma unroll
    for (int i=0;i<4;i++){ int q6=c4+i; C2s[((tl<<1)|(q6&1))*40 + (q6>>1)] = arr[i]; }
  }
  for (int e4 = tid; e4 < 512; e4 += 256){
    int n = e4>>4, p4 = (e4&15)*4;
    bf4v v = *(const bf4v*)&hstb[((size_t)c*16+h)*2048 + n*64 + p4];
    bf16 arr[4] = {v.x,v.y,v.z,v.w};
    #pragma unroll
    for (int i=0;i<4;i++) hT[(p4+i)*40 + n] = arr[i];
  }
  if (tid < 128) cse[tid] = __expf(csb[(c*4+g)*128 + tid]);
  __syncthreads();
  fv4 zz = {0.f,0.f,0.f,0.f};
  #pragma unroll
  for (int mi=0;mi<4;mi++){
    int mt = w*4 + mi;
    bfv8 a = *(const bfv8*)&C2s[(mt*16+lm)*40 + lq*8];
    #pragma unroll
    for (int nt=0;nt<4;nt++){
      bfv8 b = *(const bfv8*)&hT[(nt*16+lm)*40 + lq*8];
      fv4 s = __builtin_amdgcn_mfma_f32_16x16x32_bf16(a, b, zz, 0,0,0);
      int p = nt*16+lm;
      #pragma unroll
      for (int r=0;r<4;r++){
        int row = mt*16+lq*4+r;
        int tl = row>>1, r1 = row&1;
        size_t idx = ((size_t)(l0+tl)*16 + h)*128 + p*2 + r1;
        ypr[idx] = f2bf(bf2f(ypr[idx]) + cse[tl]*s[r]);
      }
    }
  }
}

// ---- K8B: ydown + D*silu(x), * silu(z); writes y2 into upper-half slots of ypr rows ----
__global__ void k8b_ydown(bf16* __restrict__ ypr, const float* __restrict__ Wyd,
                          const bf16* __restrict__ proj, const float* __restrict__ Dp)
{
  __shared__ __align__(16) float wsh[128*64];
  __shared__ float ysh[2048];
  int l = blockIdx.x, tid = threadIdx.x;
  for (int e=tid;e<8192;e+=256) wsh[e] = Wyd[e];
  for (int e=tid;e<2048;e+=256) ysh[e] = bf2f(ypr[(size_t)l*2048 + e]);
  __syncthreads();
  int h = tid >> 4, q0 = (tid & 15) * 4;
  float acc[4] = {};
  for (int k=0;k<128;k++){
    float yv = ysh[h*128 + k];
    float4 wv = *(const float4*)&wsh[k*64 + q0];
    acc[0]+=yv*wv.x; acc[1]+=yv*wv.y; acc[2]+=yv*wv.z; acc[3]+=yv*wv.w;
  }
  float dv = Dp[h];
  const bf16* pr = proj + (size_t)l*DPROJ;
  float4 xq = ldb4(pr + 1024 + h*64 + q0);
  float4 zq = ldb4(pr + h*64 + q0);
  float xv[4] = {xq.x,xq.y,xq.z,xq.w};
  float zv[4] = {zq.x,zq.y,zq.z,zq.w};
  float outv[4];
  #pragma unroll
  for (int i=0;i<4;i++){
    float xs = xv[i]/(1.f+__expf(-xv[i]));
    float zs = zv[i]/(1.f+__expf(-zv[i]));
    outv[i] = (acc[i] + dv*xs) * zs;
  }
  stb4(ypr + (size_t)l*2048 + h*128 + 64 + q0, make_float4(outv[0],outv[1],outv[2],outv[3]));
}

extern "C" void kernel_launch(void* const* d_in, const int* in_sizes, int n_in,
                              void* d_out, int out_size, void* d_ws, size_t ws_size,
                              hipStream_t stream) {
  const float* u       = (const float*)d_in[0];
  const float* W_in    = (const float*)d_in[1];
  const float* b_in    = (const float*)d_in[2];
  const float* W_xup   = (const float*)d_in[3];
  const float* W_ydown = (const float*)d_in[4];
  const float* A_log   = (const float*)d_in[5];
  const float* theta_l = (const float*)d_in[6];
  const float* D_p     = (const float*)d_in[7];
  const float* wB      = (const float*)d_in[8];
  const float* wC      = (const float*)d_in[9];
  const float* biasB   = (const float*)d_in[10];
  const float* biasC   = (const float*)d_in[11];
  const float* W_out   = (const float*)d_in[12];
  float* out = (float*)d_out;

  char* w = (char*)d_ws;
  bf16*  proj  = (bf16*)(w);                       // 10,518,528 B
  float* dlraw = (float*)(w + 10518528);           //     65,536 B
  float* dtb   = (float*)(w + 10584064);           //     32,768 B
  float* lamb  = (float*)(w + 10616832);           //     32,768 B
  float* csdt  = (float*)(w + 10649600);           //     32,768 B
  bf16*  Brb   = (bf16*)(w + 10682368);            //  1,048,576 B
  bf16*  Crb   = (bf16*)(w + 11730944);            //  1,048,576 B
  bf16*  xupb  = (bf16*)(w + 12779520);            //  8,388,608 B
  bf16*  hfin  = (bf16*)(w + 21168128);            //  1,048,576 B  (= partial0)
  bf16*  hstb  = (bf16*)(w + 22216704);            //  1,048,576 B  (= partial1, then hstb)
  float* dcb   = (float*)(w + 23265280);           //      1,024 B
  float* csb   = (float*)(w + 23266304);           //     32,768 B
  bf16*  ypr   = (bf16*)(w + 23299072);            //  8,388,608 B
  bf16*  WinT  = (bf16*)(w + 23299072);            //  aliased (dead once k6y writes ypr)
  bf16*  WoutT = (bf16*)(w + 10682368);            //  aliased over Brb (dead after k8a)

  tcastT<<<dim3(82,16),256,0,stream>>>(W_in, WinT, 512, DPROJ, 2624);
  gemm1_mfma<<<dim3(41,16),256,0,stream>>>(u, WinT, b_in, proj, dlraw);
  k23<<<1,256,0,stream>>>(dlraw, dtb, lamb, csdt);
  k4_rmsrope<<<2048,256,0,stream>>>(proj, wB, wC, biasB, biasC, theta_l, csdt, Brb, Crb);
  k5_xup<<<2048,256,0,stream>>>(proj, W_xup, xupb);
  k6h<<<dim3(16,16,2),256,0,stream>>>(Brb, xupb, dtb, lamb, A_log, hfin, hstb, dcb, csb);
  k6y<<<dim3(16,16,4),256,0,stream>>>(Brb, Crb, xupb, dtb, lamb, A_log, ypr);
  k7_scan<<<16,256,0,stream>>>(hfin, hstb, dcb, hstb);
  k8a_mfma<<<dim3(16,16),256,0,stream>>>(Crb, hstb, csb, ypr);
  tcastT<<<dim3(16,32),256,0,stream>>>(W_out, WoutT, 1024, 512, 512);
  k8b_ydown<<<2048,256,0,stream>>>(ypr, W_ydown, proj, D_p);
  gemmo_mfma<<<dim3(8,32),256,0,stream>>>(ypr, WoutT, out);
}

// Round 7
// 249.945 us; speedup vs baseline: 2.2157x; 1.0135x over previous
//
#include <hip/hip_runtime.h>
#include <hip/hip_bf16.h>

typedef __hip_bfloat16 bf16;
typedef __bf16 bfv8 __attribute__((ext_vector_type(8)));
typedef float fv4 __attribute__((ext_vector_type(4)));

__device__ __forceinline__ float bf2f(bf16 x){ return __bfloat162float(x); }
__device__ __forceinline__ bf16 f2bf(float x){ return __float2bfloat16(x); }
__device__ __forceinline__ float blo(unsigned u){ return __uint_as_float(u<<16); }
__device__ __forceinline__ float bhi(unsigned u){ return __uint_as_float(u & 0xffff0000u); }
struct __align__(8) bf4v { bf16 x,y,z,w; };
struct __align__(16) bf8s { ushort u[8]; };
__device__ __forceinline__ float4 ldb4(const bf16* p){
  ushort4 u = *(const ushort4*)p;
  float4 r;
  r.x = __uint_as_float(((unsigned)u.x)<<16);
  r.y = __uint_as_float(((unsigned)u.y)<<16);
  r.z = __uint_as_float(((unsigned)u.z)<<16);
  r.w = __uint_as_float(((unsigned)u.w)<<16);
  return r;
}
__device__ __forceinline__ void stb4(bf16* p, float4 v){
  bf4v t; t.x=f2bf(v.x); t.y=f2bf(v.y); t.z=f2bf(v.z); t.w=f2bf(v.w);
  *(bf4v*)p = t;
}

#define L_SEQ 2048
#define DPROJ 2568
#define NCHUNK 16
#define TCH 128

// ---------------- castU: u fp32 -> bf16 (1,048,576 elems) ----------------
__global__ void castU(const float* __restrict__ in, bf16* __restrict__ out)
{
  int i = (blockIdx.x*256 + threadIdx.x)*4;
  float4 v = *(const float4*)&in[i];
  stb4(&out[i], v);
}

// ---------------- tcastT: out[C][R] (bf16, rows padded to Cpad with zeros) = in[R][C]^T ---------
__global__ void tcastT(const float* __restrict__ in, bf16* __restrict__ out, int R, int C, int Cpad)
{
  __shared__ float t[32][33];
  int c0 = blockIdx.x*32, r0 = blockIdx.y*32;
  int tx = threadIdx.x & 31, ty = threadIdx.x >> 5;
  for (int i=0;i<32;i+=8){
    int r = r0+i+ty, cc = c0+tx;
    t[i+ty][tx] = (r<R && cc<C) ? in[(size_t)r*C+cc] : 0.f;
  }
  __syncthreads();
  for (int i=0;i<32;i+=8){
    int cc = c0+i+ty, r = r0+tx;
    if (cc<Cpad && r<R) out[(size_t)cc*R + r] = f2bf(t[tx][i+ty]);
  }
}

// ------- GEMM1 (MFMA, 128x128 tile): proj = ubf @ W_in + b_in; side fp32 for dt/lam cols -------
__global__ void __launch_bounds__(256) gemm1_mfma(const bf16* __restrict__ A, const bf16* __restrict__ BT,
                                                  const float* __restrict__ bias, bf16* __restrict__ C,
                                                  float* __restrict__ side)
{
  const int K = 512;
  __shared__ __align__(16) bf16 As[128*40];
  __shared__ __align__(16) bf16 Bs[128*40];
  int tid = threadIdx.x;
  int col0 = blockIdx.x*128, row0 = blockIdx.y*128;
  int wid = tid>>6, lane = tid&63;
  int wm = (wid&1)*64, wn = (wid>>1)*64;
  int lm = lane&15, lq = lane>>4;
  fv4 acc[4][4] = {};
  for (int k0=0;k0<K;k0+=32){
    #pragma unroll
    for (int i=0;i<2;i++){
      int e = tid + i*256;
      int r = e>>2, k8 = (e&3)*8;
      *(bf8s*)&As[r*40+k8] = *(const bf8s*)&A[(size_t)(row0+r)*K + k0 + k8];
      *(bf8s*)&Bs[r*40+k8] = *(const bf8s*)&BT[(size_t)(col0+r)*K + k0 + k8];
    }
    __syncthreads();
    bfv8 af[4], bfr[4];
    #pragma unroll
    for (int mf=0;mf<4;mf++) af[mf] = *(const bfv8*)&As[(wm+mf*16+lm)*40 + lq*8];
    #pragma unroll
    for (int nf=0;nf<4;nf++) bfr[nf] = *(const bfv8*)&Bs[(wn+nf*16+lm)*40 + lq*8];
    #pragma unroll
    for (int mf=0;mf<4;mf++)
      #pragma unroll
      for (int nf=0;nf<4;nf++)
        acc[mf][nf] = __builtin_amdgcn_mfma_f32_16x16x32_bf16(af[mf], bfr[nf], acc[mf][nf], 0,0,0);
    __syncthreads();
  }
  #pragma unroll
  for (int mf=0;mf<4;mf++){
    #pragma unroll
    for (int nf=0;nf<4;nf++){
      int gcol = col0 + wn + nf*16 + lm;
      if (gcol < DPROJ){
        float bia = bias[gcol];
        #pragma unroll
        for (int r=0;r<4;r++){
          int grow = row0 + wm + mf*16 + lq*4 + r;
          float v = acc[mf][nf][r] + bia;
          C[(size_t)grow*DPROJ + gcol] = f2bf(v);
          if (gcol >= 2560) side[grow*8 + (gcol-2560)] = v;
        }
      }
    }
  }
}

// ---------------- GEMM_OUT (MFMA): out(2048x512 fp32) = y2(interleaved ypr bf16) @ W_out --------
__global__ void __launch_bounds__(256) gemmo_mfma(const bf16* __restrict__ Yp, const bf16* __restrict__ BT,
                                                  float* __restrict__ C)
{
  const int K = 1024;
  __shared__ __align__(16) bf16 As[64*40];
  __shared__ __align__(16) bf16 Bs[64*40];
  int tid = threadIdx.x;
  int col0 = blockIdx.x*64, row0 = blockIdx.y*64;
  int wid = tid>>6, lane = tid&63;
  int wm = (wid&1)*32, wn = (wid>>1)*32;
  int lm = lane&15, lq = lane>>4;
  fv4 acc[2][2] = {};
  for (int k0=0;k0<K;k0+=32){
    {
      int m = tid>>2, k8 = (tid&3)*8;
      int kg = k0 + k8;
      *(bf8s*)&As[m*40+k8] = *(const bf8s*)&Yp[(size_t)(row0+m)*2048 + ((kg>>6)*128) + 64 + (kg&63)];
    }
    {
      int n = tid>>2, k8 = (tid&3)*8;
      *(bf8s*)&Bs[n*40+k8] = *(const bf8s*)&BT[(size_t)(col0+n)*K + k0 + k8];
    }
    __syncthreads();
    bfv8 af[2], bfr[2];
    #pragma unroll
    for (int mf=0;mf<2;mf++) af[mf] = *(const bfv8*)&As[(wm+mf*16+lm)*40 + lq*8];
    #pragma unroll
    for (int nf=0;nf<2;nf++) bfr[nf] = *(const bfv8*)&Bs[(wn+nf*16+lm)*40 + lq*8];
    #pragma unroll
    for (int mf=0;mf<2;mf++)
      #pragma unroll
      for (int nf=0;nf<2;nf++)
        acc[mf][nf] = __builtin_amdgcn_mfma_f32_16x16x32_bf16(af[mf], bfr[nf], acc[mf][nf], 0,0,0);
    __syncthreads();
  }
  #pragma unroll
  for (int mf=0;mf<2;mf++)
    #pragma unroll
    for (int nf=0;nf<2;nf++){
      int gcol = col0 + wn + nf*16 + lm;
      #pragma unroll
      for (int r=0;r<4;r++){
        int grow = row0 + wm + mf*16 + lq*4 + r;
        C[(size_t)grow*512 + gcol] = acc[mf][nf][r];
      }
    }
}

// ---------------- K23: dt = softplus, lam = sigmoid, csdt = cumsum_l(dt) (single block) ---------
__global__ void k23(const float* __restrict__ dlraw, float* __restrict__ dtb,
                    float* __restrict__ lamb, float* __restrict__ csdt)
{
  __shared__ float dts[L_SEQ*4];
  __shared__ float segs[4][64];
  int tid = threadIdx.x;
  int g = tid & 3, seg = tid >> 2;
  for (int i = 0; i < 32; i++){
    int l = seg*32 + i;
    float dr = dlraw[l*8 + g];
    float lr = dlraw[l*8 + 4 + g];
    float dt = (dr > 15.f) ? dr : log1pf(__expf(dr));
    dts[l*4+g] = dt;
    dtb[l*4+g] = dt;
    lamb[l*4+g] = 1.f/(1.f+__expf(-lr));
  }
  __syncthreads();
  float s = 0.f;
  for (int i=0;i<32;i++) s += dts[(seg*32+i)*4 + g];
  segs[g][seg] = s;
  __syncthreads();
  if (tid < 4) { float run = 0.f; for (int q=0;q<64;q++){ float t = segs[tid][q]; segs[tid][q] = run; run += t; } }
  __syncthreads();
  float run = segs[g][seg];
  for (int i=0;i<32;i++){ int l = seg*32+i; run += dts[l*4+g]; csdt[l*4+g] = run; }
}

// ------- K45: fused rmsnorm+RoPE (k4) and x_up (k5) per l ----------------
__global__ void __launch_bounds__(256) k45(
  const bf16* __restrict__ proj, const float* __restrict__ wB, const float* __restrict__ wC,
  const float* __restrict__ biasB, const float* __restrict__ biasC,
  const float* __restrict__ theta_log, const float* __restrict__ csdt,
  const float* __restrict__ Wx,
  bf16* __restrict__ Br, bf16* __restrict__ Cr, bf16* __restrict__ xup)
{
  __shared__ __align__(16) float wsm[64*128];
  __shared__ float xs[1024];
  int l = blockIdx.x, tid = threadIdx.x;
  const bf16* pr = proj + (size_t)l*DPROJ;
  // stage x_up weights + silu(x) (overlaps part-1 math)
  for (int e=tid;e<8192;e+=256) wsm[e] = Wx[e];
  for (int e=tid;e<1024;e+=256){ float v = bf2f(pr[1024+e]); xs[e] = v/(1.f+__expf(-v)); }
  // ---- part 1: rmsnorm + bias + RoPE ----
  {
    int g = tid >> 6, idx = tid & 63;
    float bv = bf2f(pr[2048 + g*64 + idx]);
    float cv = bf2f(pr[2304 + g*64 + idx]);
    float sb = bv*bv, sc = cv*cv;
    #pragma unroll
    for (int off=32; off; off>>=1){ sb += __shfl_xor(sb, off); sc += __shfl_xor(sc, off); }
    float rb = rsqrtf(sb*(1.f/64.f) + 1e-5f);
    float rc = rsqrtf(sc*(1.f/64.f) + 1e-5f);
    float bm = bv*rb*wB[idx] + biasB[g*64+idx];
    float cm = cv*rc*wC[idx] + biasC[g*64+idx];
    int k = idx >> 2;
    float ang = csdt[l*4+g] * __expf(theta_log[g*16+k]);
    float ca = cosf(ang), sa = sinf(ang);
    float bp = __shfl_xor(bm, 2);
    float cp = __shfl_xor(cm, 2);
    bool is_im = (idx >> 1) & 1;
    float bo = is_im ? (bp*sa + bm*ca) : (bm*ca - bp*sa);
    float co = is_im ? (cp*sa + cm*ca) : (cm*ca - cp*sa);
    Br[((size_t)l*4+g)*64 + idx] = f2bf(bo);
    Cr[((size_t)l*4+g)*64 + idx] = f2bf(co);
  }
  __syncthreads();
  // ---- part 2: x_up ----
  {
    int h = tid>>4, prb = (tid&15)*8;
    float acc[8] = {};
    for (int k=0;k<64;k++){
      float xv = xs[h*64+k];
      const float4* w4 = (const float4*)&wsm[k*128 + prb];
      float4 a = w4[0], b = w4[1];
      acc[0]+=xv*a.x; acc[1]+=xv*a.y; acc[2]+=xv*a.z; acc[3]+=xv*a.w;
      acc[4]+=xv*b.x; acc[5]+=xv*b.y; acc[6]+=xv*b.z; acc[7]+=xv*b.w;
    }
    bf16* o = xup + ((size_t)l*16+h)*128 + prb;
    stb4(o,   make_float4(acc[0],acc[1],acc[2],acc[3]));
    stb4(o+4, make_float4(acc[4],acc[5],acc[6],acc[7]));
  }
}

// ---------------- K6Y (MFMA): y_diag per (chunk, group, t-quarter, head) ----------------
__global__ void __launch_bounds__(256) k6y(
  const bf16* __restrict__ Br, const bf16* __restrict__ Cr, const bf16* __restrict__ xup,
  const float* __restrict__ dtb, const float* __restrict__ lamb, const float* __restrict__ A_log,
  bf16* __restrict__ ypr)
{
  __shared__ __align__(16) bf16 Cs[64*40];
  __shared__ __align__(16) bf16 Bs[64*40];
  __shared__ __align__(16) bf16 Fs[64*72];
  __shared__ __align__(16) bf16 Xs[64*72];
  __shared__ float dt_l[128], lam_l[128], cs_l[128];
  int bx = blockIdx.x; int g = bx & 3, q = bx >> 2;
  int c = blockIdx.y;
  int h4 = blockIdx.z;
  int h = g*4 + h4;
  int tid = threadIdx.x;
  int l0 = c*TCH;
  int w = tid>>6, lane = tid&63, lm = lane&15, lq = lane>>4;
  float Ah = -__expf(A_log[g]);
  float dt_prev = (c>0) ? dtb[(l0-1)*4+g] : 0.f;
  if (tid<128){ dt_l[tid] = dtb[(l0+tid)*4+g]; lam_l[tid] = lamb[(l0+tid)*4+g]; }
  __syncthreads();
  if (tid<128) cs_l[tid] = dt_l[tid]*Ah;
  __syncthreads();
  for (int off=1; off<128; off<<=1){
    float add = 0.f;
    if (tid<128 && tid>=off) add = cs_l[tid-off];
    __syncthreads();
    if (tid<128) cs_l[tid] += add;
    __syncthreads();
  }
  for (int e4 = tid; e4 < 512; e4 += 256){
    int tl = e4>>4, c4 = (e4&15)*4;
    bf4v v = *(const bf4v*)&Cr[((size_t)(l0+q*32+tl)*4+g)*64 + c4];
    bf16 arr[4] = {v.x,v.y,v.z,v.w};
    #pragma unroll
    for (int i=0;i<4;i++){ int q6=c4+i; Cs[((tl<<1)|(q6&1))*40 + (q6>>1)] = arr[i]; }
  }
  fv4 acc[4] = {};
  int nch = (q+2 < 5) ? (q+2) : 5;
  for (int kc=0; kc<nch; kc++){
    for (int e4 = tid; e4 < 512; e4 += 256){
      int jjloc = e4>>4, c4 = (e4&15)*4;
      int jj = kc*32 + jjloc; int l = l0-1+jj;
      bf4v v;
      if (l >= 0 && jj <= 128) v = *(const bf4v*)&Br[((size_t)l*4+g)*64 + c4];
      else { v.x=v.y=v.z=v.w = f2bf(0.f); }
      bf16 arr[4] = {v.x,v.y,v.z,v.w};
      #pragma unroll
      for (int i=0;i<4;i++){ int q6=c4+i; Bs[((q6&1)*32+jjloc)*40 + (q6>>1)] = arr[i]; }
    }
    for (int e4 = tid; e4 < 1024; e4 += 256){
      int jjloc = e4>>5, c4 = (e4&31)*4;
      int jj = kc*32+jjloc; int l = l0-1+jj;
      bf4v v;
      if (l>=0 && jj<=128) v = *(const bf4v*)&xup[((size_t)l*16 + h)*128 + c4];
      else { v.x=v.y=v.z=v.w = f2bf(0.f); }
      bf16 arr[4] = {v.x,v.y,v.z,v.w};
      #pragma unroll
      for (int i=0;i<4;i++){ int q7=c4+i; Xs[(q7>>1)*72 + (q7&1)*32 + jjloc] = arr[i]; }
    }
    __syncthreads();
    {
      bfv8 a = *(const bfv8*)&Cs[(w*16+lm)*40 + lq*8];
      fv4 zz = {0.f,0.f,0.f,0.f};
      #pragma unroll
      for (int nt=0;nt<4;nt++){
        bfv8 b = *(const bfv8*)&Bs[(nt*16+lm)*40 + lq*8];
        fv4 s = __builtin_amdgcn_mfma_f32_16x16x32_bf16(a, b, zz, 0,0,0);
        int col = nt*16+lm;
        int jj = kc*32 + (col&31);
        #pragma unroll
        for (int r=0;r<4;r++){
          int row = w*16 + lq*4 + r;
          int T = q*32 + (row>>1);
          float coef = 0.f; float cst = cs_l[T];
          if (jj>=1 && jj<=T+1) coef += lam_l[jj-1]*dt_l[jj-1]*__expf(cst-cs_l[jj-1]);
          if (jj<=T){ float dtx = (jj>=1)? dt_l[jj-1] : dt_prev; coef += (1.f-lam_l[jj])*dtx*__expf(cst-cs_l[jj]); }
          Fs[row*72+col] = f2bf(coef*s[r]);
        }
      }
    }
    __syncthreads();
    #pragma unroll
    for (int r2=0;r2<2;r2++){
      bfv8 a = *(const bfv8*)&Fs[(w*16+lm)*72 + r2*32 + lq*8];
      #pragma unroll
      for (int nt=0;nt<4;nt++){
        bfv8 b = *(const bfv8*)&Xs[(nt*16+lm)*72 + r2*32 + lq*8];
        acc[nt] = __builtin_amdgcn_mfma_f32_16x16x32_bf16(a, b, acc[nt], 0,0,0);
      }
    }
    __syncthreads();
  }
  #pragma unroll
  for (int nt=0;nt<4;nt++){
    int p = nt*16+lm;
    #pragma unroll
    for (int r=0;r<4;r++){
      int row = w*16+lq*4+r;
      int T = q*32+(row>>1), r1 = row&1;
      ypr[((size_t)(l0+T)*16 + h)*128 + p*2+r1] = f2bf(acc[nt][r]);
    }
  }
}

// ---------------- K6H: per (chunk,head,zhalf): partial h_final (VALU) + dcb/csb ----------------
__global__ void __launch_bounds__(256) k6h(
  const bf16* __restrict__ Br, const bf16* __restrict__ xup,
  const float* __restrict__ dtb, const float* __restrict__ lamb, const float* __restrict__ A_log,
  bf16* __restrict__ hfp0, bf16* __restrict__ hfp1, float* __restrict__ dcb, float* __restrict__ csb)
{
  __shared__ __align__(16) bf16 Bsh[65*68];
  __shared__ __align__(16) bf16 xsh[65*128];
  __shared__ float dt_l[128], lam_l[128], cs_l[128], gco[65];
  int h = blockIdx.x, c = blockIdx.y, z = blockIdx.z;
  int g = h >> 2;
  int tid = threadIdx.x;
  int l0 = c * TCH;
  int jbase = z*64;
  int nrow = z ? 65 : 64;
  float Ah = -__expf(A_log[g]);
  float dt_prev = (c > 0) ? dtb[(l0-1)*4 + g] : 0.f;
  for (int e = tid; e < nrow*16; e += 256) {
    int jjl = e >> 4, c4 = (e & 15)*4;
    int l = l0 - 1 + jbase + jjl;
    if (l >= 0) *(bf4v*)&Bsh[jjl*68 + c4] = *(const bf4v*)&Br[((size_t)l*4+g)*64 + c4];
    else { bf4v zv; zv.x=zv.y=zv.z=zv.w=f2bf(0.f); *(bf4v*)&Bsh[jjl*68 + c4] = zv; }
  }
  for (int e = tid; e < nrow*32; e += 256) {
    int jjl = e >> 5, c4 = (e & 31)*4;
    int l = l0 - 1 + jbase + jjl;
    if (l >= 0) *(bf4v*)&xsh[jjl*128 + c4] = *(const bf4v*)&xup[((size_t)l*16+h)*128 + c4];
    else { bf4v zv; zv.x=zv.y=zv.z=zv.w=f2bf(0.f); *(bf4v*)&xsh[jjl*128 + c4] = zv; }
  }
  if (tid < 128) {
    dt_l[tid]  = dtb[(l0+tid)*4+g];
    lam_l[tid] = lamb[(l0+tid)*4+g];
  }
  __syncthreads();
  if (tid < 128) cs_l[tid] = dt_l[tid] * Ah;
  __syncthreads();
  for (int off = 1; off < 128; off <<= 1) {
    float add = 0.f;
    if (tid < 128 && tid >= off) add = cs_l[tid - off];
    __syncthreads();
    if (tid < 128) cs_l[tid] += add;
    __syncthreads();
  }
  if (z == 0 && tid == 0) dcb[c*16+h] = __expf(cs_l[127]);
  if (z == 0 && (h & 3) == 0 && tid < 128) csb[(c*4+g)*128 + tid] = cs_l[tid];
  __syncthreads();
  if (tid < nrow) {
    int jj = jbase + tid;
    float gc = 0.f;
    float cst = cs_l[127];
    if (jj >= 1) gc += lam_l[jj-1]*dt_l[jj-1]*__expf(cst - cs_l[jj-1]);
    if (jj <= 127) {
      float dtx = (jj >= 1) ? dt_l[jj-1] : dt_prev;
      gc += (1.f - lam_l[jj]) * dtx * __expf(cst - cs_l[jj]);
    }
    gco[tid] = gc;
  }
  __syncthreads();
  int jstart = (z == 0 && c == 0) ? 1 : 0;
  {
    int n = tid >> 3, pg = tid & 7;
    float acc[8] = {};
    for (int jjl = jstart; jjl < nrow; jjl++) {
      float gcv = gco[jjl];
      unsigned bb = *(const unsigned*)&Bsh[jjl*68 + n*2];
      float bx = gcv*blo(bb), by = gcv*bhi(bb);
      const uint2* xr = (const uint2*)&xsh[jjl*128 + 16*pg];
      #pragma unroll
      for (int i=0;i<4;i++){
        uint2 xu = xr[i];
        float x0 = blo(xu.x), x1 = bhi(xu.x), x2 = blo(xu.y), x3 = bhi(xu.y);
        acc[2*i]   += bx*x0 + by*x1;
        acc[2*i+1] += bx*x2 + by*x3;
      }
    }
    bf16* hp = (z ? hfp1 : hfp0) + (((size_t)c*16+h)*32 + n)*64 + pg*8;
    stb4(hp,   make_float4(acc[0],acc[1],acc[2],acc[3]));
    stb4(hp+4, make_float4(acc[4],acc[5],acc[6],acc[7]));
  }
}

// ---------------- K7: inter-chunk scan (128 blocks; hfp1 aliases hstb — read-before-write) ------
__global__ void k7_scan(const bf16* __restrict__ hfp0, const bf16* __restrict__ hfp1,
                        const float* __restrict__ dcb, bf16* __restrict__ hstb)
{
  int h = blockIdx.x >> 3, seg = blockIdx.x & 7;
  int e = seg*256 + threadIdx.x;
  float carry = 0.f;
  for (int c = 0; c < NCHUNK; c++) {
    float dc = dcb[c*16+h];
    size_t base = ((size_t)c*16+h)*2048 + e;
    float p = bf2f(hfp0[base]) + bf2f(hfp1[base]);
    hstb[base] = f2bf(carry);
    carry = carry*dc + p;
  }
}

// ---------------- K8A (MFMA): ypr += cse[t] * (C' @ h^T) ----------------
__global__ void __launch_bounds__(256) k8a_mfma(const bf16* __restrict__ Cr, const bf16* __restrict__ hstb,
                                                const float* __restrict__ csb, bf16* __restrict__ ypr)
{
  __shared__ __align__(16) bf16 C2s[256*40];
  __shared__ __align__(16) bf16 hT[64*40];
  __shared__ float cse[128];
  int h = blockIdx.x, c = blockIdx.y;
  int g = h >> 2;
  int tid = threadIdx.x;
  int l0 = c*TCH;
  int w = tid>>6, lane = tid&63, lm = lane&15, lq = lane>>4;
  for (int e4 = tid; e4 < 2048; e4 += 256){
    int tl = e4>>4, c4 = (e4&15)*4;
    bf4v v = *(const bf4v*)&Cr[((size_t)(l0+tl)*4+g)*64 + c4];
    bf16 arr[4] = {v.x,v.y,v.z,v.w};
    #pragma unroll
    for (int i=0;i<4;i++){ int q6=c4+i; C2s[((tl<<1)|(q6&1))*40 + (q6>>1)] = arr[i]; }
  }
  for (int e4 = tid; e4 < 512; e4 += 256){
    int n = e4>>4, p4 = (e4&15)*4;
    bf4v v = *(const bf4v*)&hstb[((size_t)c*16+h)*2048 + n*64 + p4];
    bf16 arr[4] = {v.x,v.y,v.z,v.w};
    #pragma unroll
    for (int i=0;i<4;i++) hT[(p4+i)*40 + n] = arr[i];
  }
  if (tid < 128) cse[tid] = __expf(csb[(c*4+g)*128 + tid]);
  __syncthreads();
  fv4 zz = {0.f,0.f,0.f,0.f};
  #pragma unroll
  for (int mi=0;mi<4;mi++){
    int mt = w*4 + mi;
    bfv8 a = *(const bfv8*)&C2s[(mt*16+lm)*40 + lq*8];
    #pragma unroll
    for (int nt=0;nt<4;nt++){
      bfv8 b = *(const bfv8*)&hT[(nt*16+lm)*40 + lq*8];
      fv4 s = __builtin_amdgcn_mfma_f32_16x16x32_bf16(a, b, zz, 0,0,0);
      int p = nt*16+lm;
      #pragma unroll
      for (int r=0;r<4;r++){
        int row = mt*16+lq*4+r;
        int tl = row>>1, r1 = row&1;
        size_t idx = ((size_t)(l0+tl)*16 + h)*128 + p*2 + r1;
        ypr[idx] = f2bf(bf2f(ypr[idx]) + cse[tl]*s[r]);
      }
    }
  }
}

// ---- K8B: ydown + D*silu(x), * silu(z); writes y2 into upper-half slots of ypr rows ----
__global__ void k8b_ydown(bf16* __restrict__ ypr, const float* __restrict__ Wyd,
                          const bf16* __restrict__ proj, const float* __restrict__ Dp)
{
  __shared__ __align__(16) float wsh[128*64];
  __shared__ float ysh[2048];
  int l = blockIdx.x, tid = threadIdx.x;
  for (int e=tid;e<8192;e+=256) wsh[e] = Wyd[e];
  for (int e=tid;e<2048;e+=256) ysh[e] = bf2f(ypr[(size_t)l*2048 + e]);
  __syncthreads();
  int h = tid >> 4, q0 = (tid & 15) * 4;
  float acc[4] = {};
  for (int k=0;k<128;k++){
    float yv = ysh[h*128 + k];
    float4 wv = *(const float4*)&wsh[k*64 + q0];
    acc[0]+=yv*wv.x; acc[1]+=yv*wv.y; acc[2]+=yv*wv.z; acc[3]+=yv*wv.w;
  }
  float dv = Dp[h];
  const bf16* pr = proj + (size_t)l*DPROJ;
  float4 xq = ldb4(pr + 1024 + h*64 + q0);
  float4 zq = ldb4(pr + h*64 + q0);
  float xv[4] = {xq.x,xq.y,xq.z,xq.w};
  float zv[4] = {zq.x,zq.y,zq.z,zq.w};
  float outv[4];
  #pragma unroll
  for (int i=0;i<4;i++){
    float xs = xv[i]/(1.f+__expf(-xv[i]));
    float zs = zv[i]/(1.f+__expf(-zv[i]));
    outv[i] = (acc[i] + dv*xs) * zs;
  }
  stb4(ypr + (size_t)l*2048 + h*128 + 64 + q0, make_float4(outv[0],outv[1],outv[2],outv[3]));
}

extern "C" void kernel_launch(void* const* d_in, const int* in_sizes, int n_in,
                              void* d_out, int out_size, void* d_ws, size_t ws_size,
                              hipStream_t stream) {
  const float* u       = (const float*)d_in[0];
  const float* W_in    = (const float*)d_in[1];
  const float* b_in    = (const float*)d_in[2];
  const float* W_xup   = (const float*)d_in[3];
  const float* W_ydown = (const float*)d_in[4];
  const float* A_log   = (const float*)d_in[5];
  const float* theta_l = (const float*)d_in[6];
  const float* D_p     = (const float*)d_in[7];
  const float* wB      = (const float*)d_in[8];
  const float* wC      = (const float*)d_in[9];
  const float* biasB   = (const float*)d_in[10];
  const float* biasC   = (const float*)d_in[11];
  const float* W_out   = (const float*)d_in[12];
  float* out = (float*)d_out;

  char* w = (char*)d_ws;
  bf16*  proj  = (bf16*)(w);                       // 10,518,528 B
  float* dlraw = (float*)(w + 10518528);           //     65,536 B
  float* dtb   = (float*)(w + 10584064);           //     32,768 B
  float* lamb  = (float*)(w + 10616832);           //     32,768 B
  float* csdt  = (float*)(w + 10649600);           //     32,768 B
  bf16*  Brb   = (bf16*)(w + 10682368);            //  1,048,576 B
  bf16*  Crb   = (bf16*)(w + 11730944);            //  1,048,576 B
  bf16*  xupb  = (bf16*)(w + 12779520);            //  8,388,608 B
  bf16*  hfin  = (bf16*)(w + 21168128);            //  1,048,576 B  (= partial0)
  bf16*  hstb  = (bf16*)(w + 22216704);            //  1,048,576 B  (= partial1, then hstb)
  float* dcb   = (float*)(w + 23265280);           //      1,024 B
  float* csb   = (float*)(w + 23266304);           //     32,768 B
  bf16*  ypr   = (bf16*)(w + 23299072);            //  8,388,608 B
  bf16*  WinT  = (bf16*)(w + 23299072);            //  2688x512 bf16 aliased (dead once k6y writes ypr)
  bf16*  WoutT = (bf16*)(w + 10682368);            //  aliased over Brb (dead after k8a)
  bf16*  ubf   = (bf16*)(w + 31687680);            //  2,097,152 B

  castU<<<1024,256,0,stream>>>(u, ubf);
  tcastT<<<dim3(84,16),256,0,stream>>>(W_in, WinT, 512, DPROJ, 2688);
  gemm1_mfma<<<dim3(21,16),256,0,stream>>>(ubf, WinT, b_in, proj, dlraw);
  k23<<<1,256,0,stream>>>(dlraw, dtb, lamb, csdt);
  k45<<<2048,256,0,stream>>>(proj, wB, wC, biasB, biasC, theta_l, csdt, W_xup, Brb, Crb, xupb);
  k6h<<<dim3(16,16,2),256,0,stream>>>(Brb, xupb, dtb, lamb, A_log, hfin, hstb, dcb, csb);
  k6y<<<dim3(16,16,4),256,0,stream>>>(Brb, Crb, xupb, dtb, lamb, A_log, ypr);
  k7_scan<<<128,256,0,stream>>>(hfin, hstb, dcb, hstb);
  k8a_mfma<<<dim3(16,16),256,0,stream>>>(Crb, hstb, csb, ypr);
  tcastT<<<dim3(16,32),256,0,stream>>>(W_out, WoutT, 1024, 512, 512);
  k8b_ydown<<<2048,256,0,stream>>>(ypr, W_ydown, proj, D_p);
  gemmo_mfma<<<dim3(8,32),256,0,stream>>>(ypr, WoutT, out);
}

// Round 8
// 230.960 us; speedup vs baseline: 2.3978x; 1.0822x over previous
//
#include <hip/hip_runtime.h>
#include <hip/hip_bf16.h>

typedef __hip_bfloat16 bf16;
typedef __bf16 bfv8 __attribute__((ext_vector_type(8)));
typedef float fv4 __attribute__((ext_vector_type(4)));

__device__ __forceinline__ float bf2f(bf16 x){ return __bfloat162float(x); }
__device__ __forceinline__ bf16 f2bf(float x){ return __float2bfloat16(x); }
__device__ __forceinline__ float blo(unsigned u){ return __uint_as_float(u<<16); }
__device__ __forceinline__ float bhi(unsigned u){ return __uint_as_float(u & 0xffff0000u); }
struct __align__(8) bf4v { bf16 x,y,z,w; };
struct __align__(16) bf8s { ushort u[8]; };
__device__ __forceinline__ float4 ldb4(const bf16* p){
  ushort4 u = *(const ushort4*)p;
  float4 r;
  r.x = __uint_as_float(((unsigned)u.x)<<16);
  r.y = __uint_as_float(((unsigned)u.y)<<16);
  r.z = __uint_as_float(((unsigned)u.z)<<16);
  r.w = __uint_as_float(((unsigned)u.w)<<16);
  return r;
}
__device__ __forceinline__ void stb4(bf16* p, float4 v){
  bf4v t; t.x=f2bf(v.x); t.y=f2bf(v.y); t.z=f2bf(v.z); t.w=f2bf(v.w);
  *(bf4v*)p = t;
}

#define L_SEQ 2048
#define DPROJ 2568
#define NCHUNK 16
#define TCH 128

// ---------------- prep: castU + transpose W_in + transpose W_out, one dispatch ----------------
__device__ __forceinline__ void tbody(const float* __restrict__ in, bf16* __restrict__ out,
                                      int R, int C, int Cpad, int bx, int by, float (*t)[33])
{
  int c0 = bx*32, r0 = by*32;
  int tx = threadIdx.x & 31, ty = threadIdx.x >> 5;
  for (int i=0;i<32;i+=8){
    int r = r0+i+ty, cc = c0+tx;
    t[i+ty][tx] = (r<R && cc<C) ? in[(size_t)r*C+cc] : 0.f;
  }
  __syncthreads();
  for (int i=0;i<32;i+=8){
    int cc = c0+i+ty, r = r0+tx;
    if (cc<Cpad && r<R) out[(size_t)cc*R + r] = f2bf(t[tx][i+ty]);
  }
}

__global__ void prep(const float* __restrict__ u, bf16* __restrict__ ubf,
                     const float* __restrict__ Win, bf16* __restrict__ WinT,
                     const float* __restrict__ Wout, bf16* __restrict__ WoutT)
{
  __shared__ float t[32][33];
  int b = blockIdx.x;
  if (b < 1024){
    int i = (b*256 + threadIdx.x)*4;
    float4 v = *(const float4*)&u[i];
    stb4(&ubf[i], v);
  } else if (b < 2368){
    int idx = b - 1024;
    tbody(Win, WinT, 512, DPROJ, 2688, idx%84, idx/84, t);
  } else {
    int idx = b - 2368;
    tbody(Wout, WoutT, 1024, 512, 512, idx%16, idx/16, t);
  }
}

// ------- GEMM1 (MFMA, 128x128 tile): proj = ubf @ W_in + b_in; side fp32 for dt/lam cols -------
__global__ void __launch_bounds__(256) gemm1_mfma(const bf16* __restrict__ A, const bf16* __restrict__ BT,
                                                  const float* __restrict__ bias, bf16* __restrict__ C,
                                                  float* __restrict__ side)
{
  const int K = 512;
  __shared__ __align__(16) bf16 As[128*40];
  __shared__ __align__(16) bf16 Bs[128*40];
  int tid = threadIdx.x;
  int col0 = blockIdx.x*128, row0 = blockIdx.y*128;
  int wid = tid>>6, lane = tid&63;
  int wm = (wid&1)*64, wn = (wid>>1)*64;
  int lm = lane&15, lq = lane>>4;
  fv4 acc[4][4] = {};
  for (int k0=0;k0<K;k0+=32){
    #pragma unroll
    for (int i=0;i<2;i++){
      int e = tid + i*256;
      int r = e>>2, k8 = (e&3)*8;
      *(bf8s*)&As[r*40+k8] = *(const bf8s*)&A[(size_t)(row0+r)*K + k0 + k8];
      *(bf8s*)&Bs[r*40+k8] = *(const bf8s*)&BT[(size_t)(col0+r)*K + k0 + k8];
    }
    __syncthreads();
    bfv8 af[4], bfr[4];
    #pragma unroll
    for (int mf=0;mf<4;mf++) af[mf] = *(const bfv8*)&As[(wm+mf*16+lm)*40 + lq*8];
    #pragma unroll
    for (int nf=0;nf<4;nf++) bfr[nf] = *(const bfv8*)&Bs[(wn+nf*16+lm)*40 + lq*8];
    #pragma unroll
    for (int mf=0;mf<4;mf++)
      #pragma unroll
      for (int nf=0;nf<4;nf++)
        acc[mf][nf] = __builtin_amdgcn_mfma_f32_16x16x32_bf16(af[mf], bfr[nf], acc[mf][nf], 0,0,0);
    __syncthreads();
  }
  #pragma unroll
  for (int mf=0;mf<4;mf++){
    #pragma unroll
    for (int nf=0;nf<4;nf++){
      int gcol = col0 + wn + nf*16 + lm;
      if (gcol < DPROJ){
        float bia = bias[gcol];
        #pragma unroll
        for (int r=0;r<4;r++){
          int grow = row0 + wm + mf*16 + lq*4 + r;
          float v = acc[mf][nf][r] + bia;
          C[(size_t)grow*DPROJ + gcol] = f2bf(v);
          if (gcol >= 2560) side[grow*8 + (gcol-2560)] = v;
        }
      }
    }
  }
}

// ---------------- GEMM_OUT (MFMA): out(2048x512 fp32) = y2(interleaved ypr bf16) @ W_out --------
__global__ void __launch_bounds__(256) gemmo_mfma(const bf16* __restrict__ Yp, const bf16* __restrict__ BT,
                                                  float* __restrict__ C)
{
  const int K = 1024;
  __shared__ __align__(16) bf16 As[64*40];
  __shared__ __align__(16) bf16 Bs[64*40];
  int tid = threadIdx.x;
  int col0 = blockIdx.x*64, row0 = blockIdx.y*64;
  int wid = tid>>6, lane = tid&63;
  int wm = (wid&1)*32, wn = (wid>>1)*32;
  int lm = lane&15, lq = lane>>4;
  fv4 acc[2][2] = {};
  for (int k0=0;k0<K;k0+=32){
    {
      int m = tid>>2, k8 = (tid&3)*8;
      int kg = k0 + k8;
      *(bf8s*)&As[m*40+k8] = *(const bf8s*)&Yp[(size_t)(row0+m)*2048 + ((kg>>6)*128) + 64 + (kg&63)];
    }
    {
      int n = tid>>2, k8 = (tid&3)*8;
      *(bf8s*)&Bs[n*40+k8] = *(const bf8s*)&BT[(size_t)(col0+n)*K + k0 + k8];
    }
    __syncthreads();
    bfv8 af[2], bfr[2];
    #pragma unroll
    for (int mf=0;mf<2;mf++) af[mf] = *(const bfv8*)&As[(wm+mf*16+lm)*40 + lq*8];
    #pragma unroll
    for (int nf=0;nf<2;nf++) bfr[nf] = *(const bfv8*)&Bs[(wn+nf*16+lm)*40 + lq*8];
    #pragma unroll
    for (int mf=0;mf<2;mf++)
      #pragma unroll
      for (int nf=0;nf<2;nf++)
        acc[mf][nf] = __builtin_amdgcn_mfma_f32_16x16x32_bf16(af[mf], bfr[nf], acc[mf][nf], 0,0,0);
    __syncthreads();
  }
  #pragma unroll
  for (int mf=0;mf<2;mf++)
    #pragma unroll
    for (int nf=0;nf<2;nf++){
      int gcol = col0 + wn + nf*16 + lm;
      #pragma unroll
      for (int r=0;r<4;r++){
        int grow = row0 + wm + mf*16 + lq*4 + r;
        C[(size_t)grow*512 + gcol] = acc[mf][nf][r];
      }
    }
}

// ---------------- K23: dt = softplus, lam = sigmoid, csdt = cumsum_l(dt) (single block) ---------
__global__ void k23(const float* __restrict__ dlraw, float* __restrict__ dtb,
                    float* __restrict__ lamb, float* __restrict__ csdt)
{
  __shared__ float raw[L_SEQ*8];
  __shared__ float dts[L_SEQ*4];
  __shared__ float segs[4][64];
  int tid = threadIdx.x;
  for (int e=tid;e<L_SEQ*8;e+=256) raw[e] = dlraw[e];
  __syncthreads();
  int g = tid & 3, seg = tid >> 2;
  for (int i = 0; i < 32; i++){
    int l = seg*32 + i;
    float dr = raw[l*8 + g];
    float lr = raw[l*8 + 4 + g];
    float dt = (dr > 15.f) ? dr : log1pf(__expf(dr));
    dts[l*4+g] = dt;
    dtb[l*4+g] = dt;
    lamb[l*4+g] = 1.f/(1.f+__expf(-lr));
  }
  __syncthreads();
  float s = 0.f;
  for (int i=0;i<32;i++) s += dts[(seg*32+i)*4 + g];
  segs[g][seg] = s;
  __syncthreads();
  if (tid < 4) { float run = 0.f; for (int q=0;q<64;q++){ float t = segs[tid][q]; segs[tid][q] = run; run += t; } }
  __syncthreads();
  float run = segs[g][seg];
  for (int i=0;i<32;i++){ int l = seg*32+i; run += dts[l*4+g]; csdt[l*4+g] = run; }
}

// ------- K45: fused rmsnorm+RoPE (k4) and x_up (k5) per l ----------------
__global__ void __launch_bounds__(256) k45(
  const bf16* __restrict__ proj, const float* __restrict__ wB, const float* __restrict__ wC,
  const float* __restrict__ biasB, const float* __restrict__ biasC,
  const float* __restrict__ theta_log, const float* __restrict__ csdt,
  const float* __restrict__ Wx,
  bf16* __restrict__ Br, bf16* __restrict__ Cr, bf16* __restrict__ xup)
{
  __shared__ __align__(16) float wsm[64*128];
  __shared__ float xs[1024];
  int l = blockIdx.x, tid = threadIdx.x;
  const bf16* pr = proj + (size_t)l*DPROJ;
  for (int e=tid;e<8192;e+=256) wsm[e] = Wx[e];
  for (int e=tid;e<1024;e+=256){ float v = bf2f(pr[1024+e]); xs[e] = v/(1.f+__expf(-v)); }
  {
    int g = tid >> 6, idx = tid & 63;
    float bv = bf2f(pr[2048 + g*64 + idx]);
    float cv = bf2f(pr[2304 + g*64 + idx]);
    float sb = bv*bv, sc = cv*cv;
    #pragma unroll
    for (int off=32; off; off>>=1){ sb += __shfl_xor(sb, off); sc += __shfl_xor(sc, off); }
    float rb = rsqrtf(sb*(1.f/64.f) + 1e-5f);
    float rc = rsqrtf(sc*(1.f/64.f) + 1e-5f);
    float bm = bv*rb*wB[idx] + biasB[g*64+idx];
    float cm = cv*rc*wC[idx] + biasC[g*64+idx];
    int k = idx >> 2;
    float ang = csdt[l*4+g] * __expf(theta_log[g*16+k]);
    float ca = cosf(ang), sa = sinf(ang);
    float bp = __shfl_xor(bm, 2);
    float cp = __shfl_xor(cm, 2);
    bool is_im = (idx >> 1) & 1;
    float bo = is_im ? (bp*sa + bm*ca) : (bm*ca - bp*sa);
    float co = is_im ? (cp*sa + cm*ca) : (cm*ca - cp*sa);
    Br[((size_t)l*4+g)*64 + idx] = f2bf(bo);
    Cr[((size_t)l*4+g)*64 + idx] = f2bf(co);
  }
  __syncthreads();
  {
    int h = tid>>4, prb = (tid&15)*8;
    float acc[8] = {};
    for (int k=0;k<64;k++){
      float xv = xs[h*64+k];
      const float4* w4 = (const float4*)&wsm[k*128 + prb];
      float4 a = w4[0], b = w4[1];
      acc[0]+=xv*a.x; acc[1]+=xv*a.y; acc[2]+=xv*a.z; acc[3]+=xv*a.w;
      acc[4]+=xv*b.x; acc[5]+=xv*b.y; acc[6]+=xv*b.z; acc[7]+=xv*b.w;
    }
    bf16* o = xup + ((size_t)l*16+h)*128 + prb;
    stb4(o,   make_float4(acc[0],acc[1],acc[2],acc[3]));
    stb4(o+4, make_float4(acc[4],acc[5],acc[6],acc[7]));
  }
}

// ------- K6Y (MFMA): y_diag per (chunk, group, t-quarter, head); q==3 also emits h_final --------
__global__ void __launch_bounds__(256) k6y(
  const bf16* __restrict__ Br, const bf16* __restrict__ Cr, const bf16* __restrict__ xup,
  const float* __restrict__ dtb, const float* __restrict__ lamb, const float* __restrict__ A_log,
  bf16* __restrict__ ypr, bf16* __restrict__ hfin, float* __restrict__ dcb, float* __restrict__ csb)
{
  __shared__ __align__(16) bf16 Cs[64*40];
  __shared__ __align__(16) bf16 Bs[64*40];
  __shared__ __align__(16) bf16 Bsn[32*72];   // gco-scaled B, [n][k] (q==3 only)
  __shared__ __align__(16) bf16 Fs[64*72];
  __shared__ __align__(16) bf16 Xs[64*72];
  __shared__ float dt_l[128], lam_l[128], cs_l[128];
  int bx = blockIdx.x; int g = bx & 3, q = bx >> 2;
  int c = blockIdx.y;
  int h4 = blockIdx.z;
  int h = g*4 + h4;
  int tid = threadIdx.x;
  int l0 = c*TCH;
  int w = tid>>6, lane = tid&63, lm = lane&15, lq = lane>>4;
  float Ah = -__expf(A_log[g]);
  float dt_prev = (c>0) ? dtb[(l0-1)*4+g] : 0.f;
  if (tid<128){ dt_l[tid] = dtb[(l0+tid)*4+g]; lam_l[tid] = lamb[(l0+tid)*4+g]; }
  __syncthreads();
  if (tid<128) cs_l[tid] = dt_l[tid]*Ah;
  __syncthreads();
  for (int off=1; off<128; off<<=1){
    float add = 0.f;
    if (tid<128 && tid>=off) add = cs_l[tid-off];
    __syncthreads();
    if (tid<128) cs_l[tid] += add;
    __syncthreads();
  }
  for (int e4 = tid; e4 < 512; e4 += 256){
    int tl = e4>>4, c4 = (e4&15)*4;
    bf4v v = *(const bf4v*)&Cr[((size_t)(l0+q*32+tl)*4+g)*64 + c4];
    bf16 arr[4] = {v.x,v.y,v.z,v.w};
    #pragma unroll
    for (int i=0;i<4;i++){ int q6=c4+i; Cs[((tl<<1)|(q6&1))*40 + (q6>>1)] = arr[i]; }
  }
  fv4 acc[4] = {};
  fv4 acch[2] = {};
  int nch = (q+2 < 5) ? (q+2) : 5;
  for (int kc=0; kc<nch; kc++){
    for (int e4 = tid; e4 < 512; e4 += 256){
      int jjloc = e4>>4, c4 = (e4&15)*4;
      int jj = kc*32 + jjloc; int l = l0-1+jj;
      bf4v v;
      if (l >= 0 && jj <= 128) v = *(const bf4v*)&Br[((size_t)l*4+g)*64 + c4];
      else { v.x=v.y=v.z=v.w = f2bf(0.f); }
      bf16 arr[4] = {v.x,v.y,v.z,v.w};
      #pragma unroll
      for (int i=0;i<4;i++){ int q6=c4+i; Bs[((q6&1)*32+jjloc)*40 + (q6>>1)] = arr[i]; }
      if (q == 3){
        float cst127 = cs_l[127];
        float gcv = 0.f;
        if (jj >= 1 && jj <= 128) gcv += lam_l[jj-1]*dt_l[jj-1]*__expf(cst127 - cs_l[jj-1]);
        if (jj <= 127){ float dtx = (jj>=1)? dt_l[jj-1] : dt_prev; gcv += (1.f-lam_l[jj])*dtx*__expf(cst127 - cs_l[jj]); }
        #pragma unroll
        for (int i=0;i<4;i++){ int q6=c4+i; Bsn[(q6>>1)*72 + (q6&1)*32 + jjloc] = f2bf(gcv*bf2f(arr[i])); }
      }
    }
    for (int e4 = tid; e4 < 1024; e4 += 256){
      int jjloc = e4>>5, c4 = (e4&31)*4;
      int jj = kc*32+jjloc; int l = l0-1+jj;
      bf4v v;
      if (l>=0 && jj<=128) v = *(const bf4v*)&xup[((size_t)l*16 + h)*128 + c4];
      else { v.x=v.y=v.z=v.w = f2bf(0.f); }
      bf16 arr[4] = {v.x,v.y,v.z,v.w};
      #pragma unroll
      for (int i=0;i<4;i++){ int q7=c4+i; Xs[(q7>>1)*72 + (q7&1)*32 + jjloc] = arr[i]; }
    }
    __syncthreads();
    {
      bfv8 a = *(const bfv8*)&Cs[(w*16+lm)*40 + lq*8];
      fv4 zz = {0.f,0.f,0.f,0.f};
      #pragma unroll
      for (int nt=0;nt<4;nt++){
        bfv8 b = *(const bfv8*)&Bs[(nt*16+lm)*40 + lq*8];
        fv4 s = __builtin_amdgcn_mfma_f32_16x16x32_bf16(a, b, zz, 0,0,0);
        int col = nt*16+lm;
        int jj = kc*32 + (col&31);
        #pragma unroll
        for (int r=0;r<4;r++){
          int row = w*16 + lq*4 + r;
          int T = q*32 + (row>>1);
          float coef = 0.f; float cst = cs_l[T];
          if (jj>=1 && jj<=T+1) coef += lam_l[jj-1]*dt_l[jj-1]*__expf(cst-cs_l[jj-1]);
          if (jj<=T){ float dtx = (jj>=1)? dt_l[jj-1] : dt_prev; coef += (1.f-lam_l[jj])*dtx*__expf(cst-cs_l[jj]); }
          Fs[row*72+col] = f2bf(coef*s[r]);
        }
      }
    }
    __syncthreads();
    #pragma unroll
    for (int r2=0;r2<2;r2++){
      bfv8 a = *(const bfv8*)&Fs[(w*16+lm)*72 + r2*32 + lq*8];
      #pragma unroll
      for (int nt=0;nt<4;nt++){
        bfv8 b = *(const bfv8*)&Xs[(nt*16+lm)*72 + r2*32 + lq*8];
        acc[nt] = __builtin_amdgcn_mfma_f32_16x16x32_bf16(a, b, acc[nt], 0,0,0);
      }
    }
    if (q == 3){
      // h_final^T[p][n] += X[p][k] * Bsn[n][k]
      #pragma unroll
      for (int r2=0;r2<2;r2++){
        bfv8 a = *(const bfv8*)&Xs[(w*16+lm)*72 + r2*32 + lq*8];
        #pragma unroll
        for (int nt2=0;nt2<2;nt2++){
          bfv8 b = *(const bfv8*)&Bsn[(nt2*16+lm)*72 + r2*32 + lq*8];
          acch[nt2] = __builtin_amdgcn_mfma_f32_16x16x32_bf16(a, b, acch[nt2], 0,0,0);
        }
      }
    }
    __syncthreads();
  }
  #pragma unroll
  for (int nt=0;nt<4;nt++){
    int p = nt*16+lm;
    #pragma unroll
    for (int r=0;r<4;r++){
      int row = w*16+lq*4+r;
      int T = q*32+(row>>1), r1 = row&1;
      ypr[((size_t)(l0+T)*16 + h)*128 + p*2+r1] = f2bf(acc[nt][r]);
    }
  }
  if (q == 3){
    #pragma unroll
    for (int nt2=0;nt2<2;nt2++){
      int n = nt2*16+lm;
      #pragma unroll
      for (int r=0;r<4;r++){
        int p = w*16+lq*4+r;
        hfin[(((size_t)c*16+h)*64 + p)*32 + n] = f2bf(acch[nt2][r]);
      }
    }
    if (tid == 0) dcb[c*16+h] = __expf(cs_l[127]);
  }
  if (q == 0 && h4 == 0 && tid < 128) csb[(c*4+g)*128 + tid] = cs_l[tid];
}

// ---------------- K7: inter-chunk scan (elementwise over [p][n] state layout) ----------------
__global__ void k7_scan(const bf16* __restrict__ hfin, const float* __restrict__ dcb, bf16* __restrict__ hstb)
{
  int h = blockIdx.x >> 3, seg = blockIdx.x & 7;
  int e = seg*256 + threadIdx.x;
  float carry = 0.f;
  for (int c = 0; c < NCHUNK; c++) {
    float dc = dcb[c*16+h];
    size_t base = ((size_t)c*16+h)*2048 + e;
    float p = bf2f(hfin[base]);
    hstb[base] = f2bf(carry);
    carry = carry*dc + p;
  }
}

// ---------------- K8A (MFMA): ypr += cse[t] * (C' @ h^T); hstb layout [p][n] ----------------
__global__ void __launch_bounds__(256) k8a_mfma(const bf16* __restrict__ Cr, const bf16* __restrict__ hstb,
                                                const float* __restrict__ csb, bf16* __restrict__ ypr)
{
  __shared__ __align__(16) bf16 C2s[256*40];
  __shared__ __align__(16) bf16 hT[64*40];
  __shared__ float cse[128];
  int h = blockIdx.x, c = blockIdx.y;
  int g = h >> 2;
  int tid = threadIdx.x;
  int l0 = c*TCH;
  int w = tid>>6, lane = tid&63, lm = lane&15, lq = lane>>4;
  for (int e4 = tid; e4 < 2048; e4 += 256){
    int tl = e4>>4, c4 = (e4&15)*4;
    bf4v v = *(const bf4v*)&Cr[((size_t)(l0+tl)*4+g)*64 + c4];
    bf16 arr[4] = {v.x,v.y,v.z,v.w};
    #pragma unroll
    for (int i=0;i<4;i++){ int q6=c4+i; C2s[((tl<<1)|(q6&1))*40 + (q6>>1)] = arr[i]; }
  }
  for (int e4 = tid; e4 < 512; e4 += 256){
    int p = e4>>3, n4 = (e4&7)*4;
    bf4v v = *(const bf4v*)&hstb[((size_t)c*16+h)*2048 + p*32 + n4];
    *(bf4v*)&hT[p*40 + n4] = v;
  }
  if (tid < 128) cse[tid] = __expf(csb[(c*4+g)*128 + tid]);
  __syncthreads();
  fv4 zz = {0.f,0.f,0.f,0.f};
  #pragma unroll
  for (int mi=0;mi<4;mi++){
    int mt = w*4 + mi;
    bfv8 a = *(const bfv8*)&C2s[(mt*16+lm)*40 + lq*8];
    #pragma unroll
    for (int nt=0;nt<4;nt++){
      bfv8 b = *(const bfv8*)&hT[(nt*16+lm)*40 + lq*8];
      fv4 s = __builtin_amdgcn_mfma_f32_16x16x32_bf16(a, b, zz, 0,0,0);
      int p = nt*16+lm;
      #pragma unroll
      for (int r=0;r<4;r++){
        int row = mt*16+lq*4+r;
        int tl = row>>1, r1 = row&1;
        size_t idx = ((size_t)(l0+tl)*16 + h)*128 + p*2 + r1;
        ypr[idx] = f2bf(bf2f(ypr[idx]) + cse[tl]*s[r]);
      }
    }
  }
}

// ---- K8B: ydown + D*silu(x), * silu(z); writes y2 into upper-half slots of ypr rows ----
__global__ void k8b_ydown(bf16* __restrict__ ypr, const float* __restrict__ Wyd,
                          const bf16* __restrict__ proj, const float* __restrict__ Dp)
{
  __shared__ __align__(16) float wsh[128*64];
  __shared__ float ysh[2048];
  int l = blockIdx.x, tid = threadIdx.x;
  for (int e=tid;e<8192;e+=256) wsh[e] = Wyd[e];
  for (int e=tid;e<2048;e+=256) ysh[e] = bf2f(ypr[(size_t)l*2048 + e]);
  __syncthreads();
  int h = tid >> 4, q0 = (tid & 15) * 4;
  float acc[4] = {};
  for (int k=0;k<128;k++){
    float yv = ysh[h*128 + k];
    float4 wv = *(const float4*)&wsh[k*64 + q0];
    acc[0]+=yv*wv.x; acc[1]+=yv*wv.y; acc[2]+=yv*wv.z; acc[3]+=yv*wv.w;
  }
  float dv = Dp[h];
  const bf16* pr = proj + (size_t)l*DPROJ;
  float4 xq = ldb4(pr + 1024 + h*64 + q0);
  float4 zq = ldb4(pr + h*64 + q0);
  float xv[4] = {xq.x,xq.y,xq.z,xq.w};
  float zv[4] = {zq.x,zq.y,zq.z,zq.w};
  float outv[4];
  #pragma unroll
  for (int i=0;i<4;i++){
    float xs = xv[i]/(1.f+__expf(-xv[i]));
    float zs = zv[i]/(1.f+__expf(-zv[i]));
    outv[i] = (acc[i] + dv*xs) * zs;
  }
  stb4(ypr + (size_t)l*2048 + h*128 + 64 + q0, make_float4(outv[0],outv[1],outv[2],outv[3]));
}

extern "C" void kernel_launch(void* const* d_in, const int* in_sizes, int n_in,
                              void* d_out, int out_size, void* d_ws, size_t ws_size,
                              hipStream_t stream) {
  const float* u       = (const float*)d_in[0];
  const float* W_in    = (const float*)d_in[1];
  const float* b_in    = (const float*)d_in[2];
  const float* W_xup   = (const float*)d_in[3];
  const float* W_ydown = (const float*)d_in[4];
  const float* A_log   = (const float*)d_in[5];
  const float* theta_l = (const float*)d_in[6];
  const float* D_p     = (const float*)d_in[7];
  const float* wB      = (const float*)d_in[8];
  const float* wC      = (const float*)d_in[9];
  const float* biasB   = (const float*)d_in[10];
  const float* biasC   = (const float*)d_in[11];
  const float* W_out   = (const float*)d_in[12];
  float* out = (float*)d_out;

  char* w = (char*)d_ws;
  bf16*  proj  = (bf16*)(w);                       // 10,518,528 B
  float* dlraw = (float*)(w + 10518528);           //     65,536 B
  float* dtb   = (float*)(w + 10584064);           //     32,768 B
  float* lamb  = (float*)(w + 10616832);           //     32,768 B
  float* csdt  = (float*)(w + 10649600);           //     32,768 B
  bf16*  Brb   = (bf16*)(w + 10682368);            //  1,048,576 B
  bf16*  Crb   = (bf16*)(w + 11730944);            //  1,048,576 B
  bf16*  xupb  = (bf16*)(w + 12779520);            //  8,388,608 B
  bf16*  hfin  = (bf16*)(w + 21168128);            //  1,048,576 B
  bf16*  hstb  = (bf16*)(w + 22216704);            //  1,048,576 B
  float* dcb   = (float*)(w + 23265280);           //      1,024 B
  float* csb   = (float*)(w + 23266304);           //     32,768 B
  bf16*  ypr   = (bf16*)(w + 23299072);            //  8,388,608 B
  bf16*  WinT  = (bf16*)(w + 23299072);            //  aliased over ypr (dead once k6y writes ypr)
  bf16*  ubf   = (bf16*)(w + 31687680);            //  2,097,152 B
  bf16*  WoutT = (bf16*)(w + 33784832);            //  1,048,576 B (own slot — no aliasing)

  prep<<<2880,256,0,stream>>>(u, ubf, W_in, WinT, W_out, WoutT);
  gemm1_mfma<<<dim3(21,16),256,0,stream>>>(ubf, WinT, b_in, proj, dlraw);
  k23<<<1,256,0,stream>>>(dlraw, dtb, lamb, csdt);
  k45<<<2048,256,0,stream>>>(proj, wB, wC, biasB, biasC, theta_l, csdt, W_xup, Brb, Crb, xupb);
  k6y<<<dim3(16,16,4),256,0,stream>>>(Brb, Crb, xupb, dtb, lamb, A_log, ypr, hfin, dcb, csb);
  k7_scan<<<128,256,0,stream>>>(hfin, dcb, hstb);
  k8a_mfma<<<dim3(16,16),256,0,stream>>>(Crb, hstb, csb, ypr);
  k8b_ydown<<<2048,256,0,stream>>>(ypr, W_ydown, proj, D_p);
  gemmo_mfma<<<dim3(8,32),256,0,stream>>>(ypr, WoutT, out);
}